// Round 14
// baseline (175.247 us; speedup 1.0000x reference)
//
#include <hip/hip_runtime.h>
#include <hip/hip_bf16.h>

#define DEV static __device__ __forceinline__

typedef __attribute__((ext_vector_type(8))) short bf16x8;
typedef __attribute__((ext_vector_type(4))) short s16x4;
typedef __attribute__((ext_vector_type(4))) float f32x4;
typedef __attribute__((ext_vector_type(2))) float f32x2;

DEV float wsum(float v) {
  v += __shfl_xor(v, 1);  v += __shfl_xor(v, 2);  v += __shfl_xor(v, 4);
  v += __shfl_xor(v, 8);  v += __shfl_xor(v, 16); v += __shfl_xor(v, 32);
  return v;
}
DEV float wmaxr(float v) {
  v = fmaxf(v, __shfl_xor(v, 1));  v = fmaxf(v, __shfl_xor(v, 2));
  v = fmaxf(v, __shfl_xor(v, 4));  v = fmaxf(v, __shfl_xor(v, 8));
  v = fmaxf(v, __shfl_xor(v, 16)); v = fmaxf(v, __shfl_xor(v, 32));
  return v;
}
DEV short f2bf(float x) {
  __hip_bfloat16 h = __float2bfloat16(x);
  return *reinterpret_cast<short*>(&h);
}
DEV float bf2f(unsigned int u) {
  const unsigned int x = u << 16;
  return __uint_as_float(x);
}
DEV float bfs2f(short s) {
  const unsigned int x = ((unsigned int)(unsigned short)s) << 16;
  return __uint_as_float(x);
}

// ---------------------------------------------------------------------------
// Unified bf16 MFMA GEMM: depth-2 register prefetch + LDS double buffer.
// (unchanged from round 12/13 — HW-validated)
// ---------------------------------------------------------------------------
template <int TRANSB, int ADDD, int ABF16, int OUTBF16>
__global__ __launch_bounds__(256) void gemm_mfma_k(
    const void* __restrict__ Av, int lda, long long bsA,
    const float* __restrict__ B, int ldb, long long bsB,
    void* __restrict__ Cv, int ldc, long long bsC,
    const float* __restrict__ D, long long ldd,
    int M, int N, int K)
{
  const float* Af = (const float*)Av + (ABF16 ? 0 : (size_t)blockIdx.z * bsA);
  const short* Ah = (const short*)Av + (ABF16 ? (size_t)blockIdx.z * bsA : 0);
  B += (size_t)blockIdx.z * bsB;
  const int m0 = blockIdx.y * 64, n0 = blockIdx.x * 64;
  const int tid = threadIdx.x;
  const int w = tid >> 6, lane = tid & 63;
  const int wr = w >> 1, wc = w & 1;
  __shared__ __attribute__((aligned(16))) short As[2][64][40];
  __shared__ __attribute__((aligned(16))) short Bs[2][64][40];
  f32x4 acc[2][2] = {};

  const int ar = tid >> 2, akc = (tid & 3) * 8;
  const int br = tid >> 3, bnc = (tid & 7) * 8;
  const bool arv = (m0 + ar < M);
  const int rbase = wr * 32 + (lane & 15);
  const int cbase = wc * 32 + (lane & 15);
  const int kb = (lane >> 4) * 8;

  auto gload = [&](int k0, float4& a0, float4& a1, bf16x8& ah,
                   float4& b0, float4& b1) {
    if (ABF16) {
      ah = bf16x8{};
      if (arv) ah = *(const bf16x8*)(Ah + (size_t)(m0 + ar) * lda + k0 + akc);
    } else {
      a0 = make_float4(0.f, 0.f, 0.f, 0.f); a1 = a0;
      if (arv) {
        a0 = *(const float4*)(Af + (size_t)(m0 + ar) * lda + k0 + akc);
        a1 = *(const float4*)(Af + (size_t)(m0 + ar) * lda + k0 + akc + 4);
      }
    }
    if (TRANSB) {
      b0 = *(const float4*)(B + (size_t)(n0 + ar) * ldb + k0 + akc);
      b1 = *(const float4*)(B + (size_t)(n0 + ar) * ldb + k0 + akc + 4);
    } else {
      b0 = *(const float4*)(B + (size_t)(k0 + br) * ldb + n0 + bnc);
      b1 = *(const float4*)(B + (size_t)(k0 + br) * ldb + n0 + bnc + 4);
    }
  };
  auto stage = [&](int buf, const float4& a0, const float4& a1, const bf16x8& ah,
                   const float4& b0, const float4& b1) {
    if (ABF16) {
      *(bf16x8*)&As[buf][ar][akc] = ah;
    } else {
      bf16x8 av;
      av[0] = f2bf(a0.x); av[1] = f2bf(a0.y); av[2] = f2bf(a0.z); av[3] = f2bf(a0.w);
      av[4] = f2bf(a1.x); av[5] = f2bf(a1.y); av[6] = f2bf(a1.z); av[7] = f2bf(a1.w);
      *(bf16x8*)&As[buf][ar][akc] = av;
    }
    if (TRANSB) {
      bf16x8 bv;
      bv[0] = f2bf(b0.x); bv[1] = f2bf(b0.y); bv[2] = f2bf(b0.z); bv[3] = f2bf(b0.w);
      bv[4] = f2bf(b1.x); bv[5] = f2bf(b1.y); bv[6] = f2bf(b1.z); bv[7] = f2bf(b1.w);
      *(bf16x8*)&Bs[buf][ar][akc] = bv;
    } else {
      Bs[buf][bnc + 0][br] = f2bf(b0.x); Bs[buf][bnc + 1][br] = f2bf(b0.y);
      Bs[buf][bnc + 2][br] = f2bf(b0.z); Bs[buf][bnc + 3][br] = f2bf(b0.w);
      Bs[buf][bnc + 4][br] = f2bf(b1.x); Bs[buf][bnc + 5][br] = f2bf(b1.y);
      Bs[buf][bnc + 6][br] = f2bf(b1.z); Bs[buf][bnc + 7][br] = f2bf(b1.w);
    }
  };
  auto compute = [&](int buf) {
    bf16x8 af0 = *(const bf16x8*)&As[buf][rbase][kb];
    bf16x8 af1 = *(const bf16x8*)&As[buf][rbase + 16][kb];
    bf16x8 bf0 = *(const bf16x8*)&Bs[buf][cbase][kb];
    bf16x8 bf1 = *(const bf16x8*)&Bs[buf][cbase + 16][kb];
    acc[0][0] = __builtin_amdgcn_mfma_f32_16x16x32_bf16(af0, bf0, acc[0][0], 0, 0, 0);
    acc[0][1] = __builtin_amdgcn_mfma_f32_16x16x32_bf16(af0, bf1, acc[0][1], 0, 0, 0);
    acc[1][0] = __builtin_amdgcn_mfma_f32_16x16x32_bf16(af1, bf0, acc[1][0], 0, 0, 0);
    acc[1][1] = __builtin_amdgcn_mfma_f32_16x16x32_bf16(af1, bf1, acc[1][1], 0, 0, 0);
  };

  float4 a0A, a1A, b0A, b1A, a0B, a1B, b0B, b1B;
  bf16x8 ahA = {}, ahB = {};
  gload(0, a0A, a1A, ahA, b0A, b1A);
  gload(32, a0B, a1B, ahB, b0B, b1B);
  for (int k0 = 0; k0 < K; k0 += 64) {
    stage(0, a0A, a1A, ahA, b0A, b1A);
    if (k0 + 64 < K) gload(k0 + 64, a0A, a1A, ahA, b0A, b1A);
    __syncthreads();
    compute(0);
    stage(1, a0B, a1B, ahB, b0B, b1B);
    if (k0 + 96 < K) gload(k0 + 96, a0B, a1B, ahB, b0B, b1B);
    __syncthreads();
    compute(1);
  }

  const size_t cb = (size_t)blockIdx.z * (size_t)bsC;
#pragma unroll
  for (int mi = 0; mi < 2; ++mi)
#pragma unroll
    for (int ni = 0; ni < 2; ++ni)
#pragma unroll
      for (int r = 0; r < 4; ++r) {
        const int row = m0 + wr * 32 + mi * 16 + (lane >> 4) * 4 + r;
        const int col = n0 + wc * 32 + ni * 16 + (lane & 15);
        if (row < M) {
          float v = acc[mi][ni][r];
          if (ADDD) v += D[(size_t)row * ldd + col];
          if (OUTBF16)
            ((__hip_bfloat16*)Cv)[cb + (size_t)row * ldc + col] = __float2bfloat16(v);
          else
            ((float*)Cv)[cb + (size_t)row * ldc + col] = v;
        }
      }
}

// ---------------------------------------------------------------------------
// bf16 MFMA GEMM with LayerNorm fused on A (unchanged).
// ---------------------------------------------------------------------------
__global__ __launch_bounds__(256) void gemm_mfma_lnA_k(
    const float* __restrict__ A, long long lda,
    const float* __restrict__ g, const float* __restrict__ b,
    const float* __restrict__ B, int ldb,
    float* __restrict__ C, int ldc,
    int M, int N, int K)
{
  const int m0 = blockIdx.y * 64, n0 = blockIdx.x * 64;
  const int tid = threadIdx.x;
  const int w = tid >> 6, lane = tid & 63;
  const int wr = w >> 1, wc = w & 1;
  __shared__ __attribute__((aligned(16))) short As[2][64][40];
  __shared__ __attribute__((aligned(16))) short Bs[2][64][40];
  __shared__ __attribute__((aligned(16))) float g_s[512], b_s[512];
  __shared__ float mean_s[64], rstd_s[64];
  f32x4 acc[2][2] = {};

  if (tid < 128) ((float4*)g_s)[tid] = ((const float4*)g)[tid];
  else ((float4*)b_s)[tid - 128] = ((const float4*)b)[tid - 128];

  {
    const int r = tid >> 2, p = tid & 3;
    float s = 0.f, ss = 0.f;
    if (m0 + r < M) {
      const float4* src = (const float4*)(A + (size_t)(m0 + r) * lda + p * 128);
#pragma unroll 8
      for (int i = 0; i < 32; ++i) {
        const float4 v = src[i];
        s += v.x + v.y + v.z + v.w;
        ss += v.x * v.x + v.y * v.y + v.z * v.z + v.w * v.w;
      }
    }
    s += __shfl_xor(s, 1);  s += __shfl_xor(s, 2);
    ss += __shfl_xor(ss, 1); ss += __shfl_xor(ss, 2);
    if (p == 0) {
      const float mean = s * (1.f / 512.f);
      mean_s[r] = mean;
      rstd_s[r] = rsqrtf(ss * (1.f / 512.f) - mean * mean + 1e-5f);
    }
  }
  __syncthreads();

  const int ar = tid >> 2, akc = (tid & 3) * 8;
  const int br = tid >> 3, bnc = (tid & 7) * 8;
  const bool arv = (m0 + ar < M);
  const int rbase = wr * 32 + (lane & 15);
  const int cbase = wc * 32 + (lane & 15);
  const int kb = (lane >> 4) * 8;

  auto gload = [&](int k0, float4& a0, float4& a1, float4& b0, float4& b1) {
    a0 = make_float4(0.f, 0.f, 0.f, 0.f); a1 = a0;
    if (arv) {
      a0 = *(const float4*)(A + (size_t)(m0 + ar) * lda + k0 + akc);
      a1 = *(const float4*)(A + (size_t)(m0 + ar) * lda + k0 + akc + 4);
    }
    b0 = *(const float4*)(B + (size_t)(k0 + br) * ldb + n0 + bnc);
    b1 = *(const float4*)(B + (size_t)(k0 + br) * ldb + n0 + bnc + 4);
  };
  auto stage = [&](int buf, int k0, const float4& a0, const float4& a1,
                   const float4& b0, const float4& b1) {
    const float mn = mean_s[ar], rs = rstd_s[ar];
    const int kc = k0 + akc;
    bf16x8 av;
    av[0] = f2bf((a0.x - mn) * rs * g_s[kc + 0] + b_s[kc + 0]);
    av[1] = f2bf((a0.y - mn) * rs * g_s[kc + 1] + b_s[kc + 1]);
    av[2] = f2bf((a0.z - mn) * rs * g_s[kc + 2] + b_s[kc + 2]);
    av[3] = f2bf((a0.w - mn) * rs * g_s[kc + 3] + b_s[kc + 3]);
    av[4] = f2bf((a1.x - mn) * rs * g_s[kc + 4] + b_s[kc + 4]);
    av[5] = f2bf((a1.y - mn) * rs * g_s[kc + 5] + b_s[kc + 5]);
    av[6] = f2bf((a1.z - mn) * rs * g_s[kc + 6] + b_s[kc + 6]);
    av[7] = f2bf((a1.w - mn) * rs * g_s[kc + 7] + b_s[kc + 7]);
    *(bf16x8*)&As[buf][ar][akc] = av;
    Bs[buf][bnc + 0][br] = f2bf(b0.x); Bs[buf][bnc + 1][br] = f2bf(b0.y);
    Bs[buf][bnc + 2][br] = f2bf(b0.z); Bs[buf][bnc + 3][br] = f2bf(b0.w);
    Bs[buf][bnc + 4][br] = f2bf(b1.x); Bs[buf][bnc + 5][br] = f2bf(b1.y);
    Bs[buf][bnc + 6][br] = f2bf(b1.z); Bs[buf][bnc + 7][br] = f2bf(b1.w);
  };
  auto compute = [&](int buf) {
    bf16x8 af0 = *(const bf16x8*)&As[buf][rbase][kb];
    bf16x8 af1 = *(const bf16x8*)&As[buf][rbase + 16][kb];
    bf16x8 bf0 = *(const bf16x8*)&Bs[buf][cbase][kb];
    bf16x8 bf1 = *(const bf16x8*)&Bs[buf][cbase + 16][kb];
    acc[0][0] = __builtin_amdgcn_mfma_f32_16x16x32_bf16(af0, bf0, acc[0][0], 0, 0, 0);
    acc[0][1] = __builtin_amdgcn_mfma_f32_16x16x32_bf16(af0, bf1, acc[0][1], 0, 0, 0);
    acc[1][0] = __builtin_amdgcn_mfma_f32_16x16x32_bf16(af1, bf0, acc[1][0], 0, 0, 0);
    acc[1][1] = __builtin_amdgcn_mfma_f32_16x16x32_bf16(af1, bf1, acc[1][1], 0, 0, 0);
  };

  float4 a0A, a1A, b0A, b1A, a0B, a1B, b0B, b1B;
  gload(0, a0A, a1A, b0A, b1A);
  gload(32, a0B, a1B, b0B, b1B);
  for (int k0 = 0; k0 < K; k0 += 64) {
    stage(0, k0, a0A, a1A, b0A, b1A);
    if (k0 + 64 < K) gload(k0 + 64, a0A, a1A, b0A, b1A);
    __syncthreads();
    compute(0);
    stage(1, k0 + 32, a0B, a1B, b0B, b1B);
    if (k0 + 96 < K) gload(k0 + 96, a0B, a1B, b0B, b1B);
    __syncthreads();
    compute(1);
  }

#pragma unroll
  for (int mi = 0; mi < 2; ++mi)
#pragma unroll
    for (int ni = 0; ni < 2; ++ni)
#pragma unroll
      for (int r = 0; r < 4; ++r) {
        const int row = m0 + wr * 32 + mi * 16 + (lane >> 4) * 4 + r;
        const int col = n0 + wc * 32 + ni * 16 + (lane & 15);
        if (row < M) C[(size_t)row * ldc + col] = acc[mi][ni][r];
      }
}

// ---------------------------------------------------------------------------
// Logits GEMM with fused L2 norms (unchanged).
// ---------------------------------------------------------------------------
__global__ __launch_bounds__(256) void logits_k(
    const float* __restrict__ A, int lda,
    const float* __restrict__ B, int ldb,
    float* __restrict__ C, int ldc,
    const float* __restrict__ alpha_ptr,
    int M, int N, int K)
{
  const int m0 = blockIdx.y * 32, n0 = blockIdx.x * 64;
  const int tid = threadIdx.x;
  __shared__ __attribute__((aligned(16))) float As[2][16][36];
  __shared__ __attribute__((aligned(16))) float Bs[2][16][68];
  __shared__ float nA[32], nB[64];
  float acc[2][4] = {};
  float ssA = 0.f, ssB = 0.f;
  const int ty = tid >> 4, tx = tid & 15;
  const int am = tid >> 3, ak = (tid & 7) * 2;
  const int bm = tid >> 2, bt = (tid & 3) * 4;
  const bool aval = (m0 + am < M);
  const bool bval = (n0 + bm < N);

  float2 av; float4 bv;
  auto gload = [&](int k0) {
    av = make_float2(0.f, 0.f);
    bv = make_float4(0.f, 0.f, 0.f, 0.f);
    if (aval) av = *(const float2*)(A + (size_t)(m0 + am) * lda + (k0 + ak));
    if (bval) bv = *(const float4*)(B + (size_t)(n0 + bm) * ldb + (k0 + bt));
    ssA += av.x * av.x + av.y * av.y;
    ssB += bv.x * bv.x + bv.y * bv.y + bv.z * bv.z + bv.w * bv.w;
  };
  auto sstore = [&](int buf) {
    As[buf][ak][am] = av.x; As[buf][ak + 1][am] = av.y;
    Bs[buf][bt + 0][bm] = bv.x; Bs[buf][bt + 1][bm] = bv.y;
    Bs[buf][bt + 2][bm] = bv.z; Bs[buf][bt + 3][bm] = bv.w;
  };

  const int nIt = K >> 4;
  gload(0); sstore(0);
  for (int it = 0; it < nIt; ++it) {
    __syncthreads();
    if (it + 1 < nIt) gload((it + 1) << 4);
    const int buf = it & 1;
#pragma unroll
    for (int kk = 0; kk < 16; ++kk) {
      const float2 a  = *(const float2*)&As[buf][kk][ty * 2];
      const float4 bq = *(const float4*)&Bs[buf][kk][tx * 4];
      acc[0][0] += a.x * bq.x; acc[0][1] += a.x * bq.y; acc[0][2] += a.x * bq.z; acc[0][3] += a.x * bq.w;
      acc[1][0] += a.y * bq.x; acc[1][1] += a.y * bq.y; acc[1][2] += a.y * bq.z; acc[1][3] += a.y * bq.w;
    }
    if (it + 1 < nIt) sstore((it + 1) & 1);
  }

  ssA += __shfl_xor(ssA, 1); ssA += __shfl_xor(ssA, 2); ssA += __shfl_xor(ssA, 4);
  if ((tid & 7) == 0) nA[am] = rsqrtf(ssA);
  ssB += __shfl_xor(ssB, 1); ssB += __shfl_xor(ssB, 2);
  if ((tid & 3) == 0) nB[bm] = rsqrtf(ssB);
  __syncthreads();

  const float alpha = __expf(alpha_ptr[0]);
#pragma unroll
  for (int i = 0; i < 2; ++i) {
    const int m = m0 + ty * 2 + i;
    if (m >= M) continue;
    const float fa = alpha * nA[ty * 2 + i];
#pragma unroll
    for (int j = 0; j < 4; ++j) {
      const int nn = n0 + tx * 4 + j;
      if (nn < N) C[(size_t)m * ldc + nn] = acc[i][j] * fa * nB[tx * 4 + j];
    }
  }
}

// ---------------------------------------------------------------------------
// FUSED sweep v9 — MFMA scores. Per class: stage X' = x*g (bf16) in LDS,
// scores[16 heads pad][80 rows pad] = WT(global bf16 A-frags) @ X'^T via
// v_mfma_f32_16x16x32_bf16 (B-frag = Xs[row][k], HW-validated layout).
// All wsum/fold8/exp leave the hot loop: exp once centrally, accumulate is
// a shuffle-free LDS-fed FMA stream. Scaled-ctx scores derived analytically
// from unscaled GEMM outputs (z2 = c*zraw; rstd2 from var = 1/rstd^2 - eps).
// ---------------------------------------------------------------------------
__global__ __launch_bounds__(256) void fused_sweep_kernel(
    const float* __restrict__ ctx, const float* __restrict__ cls,
    const float* __restrict__ g, const float* __restrict__ b,
    const __hip_bfloat16* __restrict__ wt, __hip_bfloat16* __restrict__ u_out)
{
  const int n = blockIdx.x, tid = threadIdx.x;
  const int w = tid >> 6, lane = tid & 63;
  constexpr int XP = 516;   // Xs row stride in shorts (bank-spread)
  __shared__ __attribute__((aligned(16))) short Xs[80][XP];   // x*g (bf16)
  __shared__ __attribute__((aligned(16))) float g_s[512], b_s[512];
  __shared__ __attribute__((aligned(16))) short h2_s[5][512];
  __shared__ float mean_s[80], rstd_s[80];
  __shared__ float sc_s[8][80];
  __shared__ float es_s[8][72];
  __shared__ float zraw_s[8][5];
  __shared__ float sc2_s[8][5];
  __shared__ float ah_s[8][5];
  __shared__ float wstatB[4][8], wstatL[4][8];
  __shared__ float attr_s[5];
  __shared__ float Sgw_l[8], bw_l[8];
  __shared__ float Bt_s[8], Lt_s[8], inv_s[8];
  __shared__ float e2_s[8][5];

  // ---- phase 0: g/b to LDS
  if (tid < 128) ((float4*)g_s)[tid] = ((const float4*)g)[tid];
  else ((float4*)b_s)[tid - 128] = ((const float4*)b)[tid - 128];
  __syncthreads();

  const short* wtS = (const short*)wt + (size_t)n * 4096;

  // ---- phase 1: load X rows (0-4 ctx, 5-76 cls): stats + scale-by-g + bf16
  auto loadrow = [&](int row, int p) {
    const float* src = (row < 5)
        ? ctx + ((size_t)n * 5 + row) * 512 + p * 128
        : cls + ((size_t)n * 72 + (row - 5)) * 512 + p * 128;
    float s = 0.f, ss = 0.f;
    for (int c2 = 0; c2 < 4; ++c2) {
      float4 xv[8];
#pragma unroll
      for (int i = 0; i < 8; ++i) xv[i] = ((const float4*)src)[c2 * 8 + i];
#pragma unroll
      for (int i = 0; i < 8; ++i) {
        s  += xv[i].x + xv[i].y + xv[i].z + xv[i].w;
        ss += xv[i].x * xv[i].x + xv[i].y * xv[i].y
            + xv[i].z * xv[i].z + xv[i].w * xv[i].w;
        const int j = p * 128 + c2 * 32 + i * 4;
        const float4 gg = *(const float4*)&g_s[j];
        s16x4 o;
        o[0] = f2bf(xv[i].x * gg.x); o[1] = f2bf(xv[i].y * gg.y);
        o[2] = f2bf(xv[i].z * gg.z); o[3] = f2bf(xv[i].w * gg.w);
        *(s16x4*)&Xs[row][j] = o;
      }
    }
    s += __shfl_xor(s, 1);  s += __shfl_xor(s, 2);
    ss += __shfl_xor(ss, 1); ss += __shfl_xor(ss, 2);
    if (p == 0) {
      const float mean = s * (1.f / 512.f);
      mean_s[row] = mean;
      rstd_s[row] = rsqrtf(ss * (1.f / 512.f) - mean * mean + 1e-5f);
    }
  };
  loadrow(tid >> 2, tid & 3);                       // rows 0..63
  if (tid < 52) {
    loadrow(64 + (tid >> 2), tid & 3);              // rows 64..76
  } else if (w >= 1) {
    // Sgw = sum g*wt, bw = sum b*wt per head (waves 1-3)
    for (int h = w - 1; h < 8; h += 3) {
      const bf16x8 wv = *(const bf16x8*)(wtS + h * 512 + lane * 8);
      float s1 = 0.f, s2 = 0.f;
#pragma unroll
      for (int i = 0; i < 8; ++i) {
        const float wf = bfs2f(wv[i]);
        s1 += wf * g_s[lane * 8 + i];
        s2 += wf * b_s[lane * 8 + i];
      }
      s1 = wsum(s1); s2 = wsum(s2);
      if (lane == 0) { Sgw_l[h] = s1; bw_l[h] = s2; }
    }
  }
  __syncthreads();

  // ---- phase 2: MFMA scores C'[head 16][row 80] = WT @ X'^T
  for (int t = w; t < 5; t += 4) {
    f32x4 acc = {};
#pragma unroll
    for (int kt = 0; kt < 16; ++kt) {
      const bf16x8 af = *(const bf16x8*)(wtS + (lane & 15) * 512 + kt * 32 + (lane >> 4) * 8);
      const bf16x8 bf = *(const bf16x8*)&Xs[t * 16 + (lane & 15)][kt * 32 + (lane >> 4) * 8];
      acc = __builtin_amdgcn_mfma_f32_16x16x32_bf16(af, bf, acc, 0, 0, 0);
    }
    const int row = t * 16 + (lane & 15);
#pragma unroll
    for (int r = 0; r < 4; ++r) {
      const int h = (lane >> 4) * 4 + r;
      if (h < 8 && row < 77) {
        sc_s[h][row] = rstd_s[row] * 0.125f * (acc[r] - mean_s[row] * Sgw_l[h])
                     + 0.125f * bw_l[h];
        if (row < 5) zraw_s[h][row] = acc[r];
      }
    }
  }
  __syncthreads();

  // ---- phase 3: pass-1 softmax over 77 -> head-mean of first 5 -> attr
  for (int hh = w; hh < 8; hh += 4) {
    const float v0 = sc_s[hh][lane];
    const float v1 = (lane + 64 < 77) ? sc_s[hh][lane + 64] : -1e30f;
    const float mx = wmaxr(fmaxf(v0, v1));
    const float e0 = __expf(v0 - mx);
    const float e1 = (lane + 64 < 77) ? __expf(v1 - mx) : 0.f;
    const float S = wsum(e0 + e1);
    if (lane < 5) ah_s[hh][lane] = e0 / S;
  }
  __syncthreads();
  // attr (tid 0) + central exp table es (all threads)
  if (tid == 0) {
    float m[5], mx = -1e30f;
#pragma unroll
    for (int p = 0; p < 5; ++p) {
      float acc = 0.f;
      for (int hh = 0; hh < 8; ++hh) acc += ah_s[hh][p];
      m[p] = acc * 0.125f;
      mx = fmaxf(mx, m[p]);
    }
    float e[5], S = 0.f;
#pragma unroll
    for (int p = 0; p < 5; ++p) { e[p] = __expf(m[p] - mx); S += e[p]; }
#pragma unroll
    for (int p = 0; p < 5; ++p) attr_s[p] = e[p] / S;
  }
  for (int idx = tid; idx < 576; idx += 256) {
    const int h = idx / 72, k = idx % 72;
    es_s[h][k] = __expf(sc_s[h][k + 5]);
  }
  __syncthreads();

  // ---- phase 4a: stage C — scaled ctx: scores analytic + h2 from Xs
  for (int k = w; k < 5; k += 4) {
    const float c = attr_s[k];
    const float mean = mean_s[k], rstd1 = rstd_s[k];
    const float var = 1.f / (rstd1 * rstd1) - 1e-5f;
    const float rstd2 = rsqrtf(c * c * var + 1e-5f);
    if (lane < 8)
      sc2_s[lane][k] = rstd2 * 0.125f * (c * zraw_s[lane][k] - c * mean * Sgw_l[lane])
                     + 0.125f * bw_l[lane];
    const float cr = c * rstd2;
    const int j0 = lane * 4, j1 = j0 + 256;
#pragma unroll
    for (int half = 0; half < 2; ++half) {
      const int j = half ? j1 : j0;
      const s16x4 xq = *(const s16x4*)&Xs[k][j];
      const float4 gg = *(const float4*)&g_s[j];
      const float4 bb = *(const float4*)&b_s[j];
      s16x4 o;
      o[0] = f2bf(cr * (bfs2f(xq[0]) - mean * gg.x) + bb.x);
      o[1] = f2bf(cr * (bfs2f(xq[1]) - mean * gg.y) + bb.y);
      o[2] = f2bf(cr * (bfs2f(xq[2]) - mean * gg.z) + bb.z);
      o[3] = f2bf(cr * (bfs2f(xq[3]) - mean * gg.w) + bb.w);
      *(s16x4*)&h2_s[k][j] = o;
    }
  }

  // ---- phase 4b: accumulate A' = sum er*(x*g), B = sum er*mean, L = sum es
  f32x2 A2[8][4];
#pragma unroll
  for (int hh = 0; hh < 8; ++hh)
#pragma unroll
    for (int i = 0; i < 4; ++i) A2[hh][i] = f32x2{0.f, 0.f};
  float B8[8] = {}, L8[8] = {};
  {
    const int j0 = lane * 4, j1 = j0 + 256;
#pragma unroll 2
    for (int k = 5 + w; k < 77; k += 4) {
      const s16x4 x0q = *(const s16x4*)&Xs[k][j0];
      const s16x4 x1q = *(const s16x4*)&Xs[k][j1];
      const float rstd = rstd_s[k], mean = mean_s[k];
      const f32x2 q0 = f32x2{bfs2f(x0q[0]), bfs2f(x0q[1])};
      const f32x2 q1 = f32x2{bfs2f(x0q[2]), bfs2f(x0q[3])};
      const f32x2 q2 = f32x2{bfs2f(x1q[0]), bfs2f(x1q[1])};
      const f32x2 q3 = f32x2{bfs2f(x1q[2]), bfs2f(x1q[3])};
#pragma unroll
      for (int hh = 0; hh < 8; ++hh) {
        const float es = es_s[hh][k - 5];
        const float er = es * rstd;
        const f32x2 ev = f32x2{er, er};
        A2[hh][0] += ev * q0; A2[hh][1] += ev * q1;
        A2[hh][2] += ev * q2; A2[hh][3] += ev * q3;
        B8[hh] += er * mean;
        L8[hh] += es;
      }
    }
  }
  if (lane == 0)
#pragma unroll
    for (int hh = 0; hh < 8; ++hh) {
      wstatB[w][hh] = B8[hh]; wstatL[w][hh] = L8[hh];
    }
  __syncthreads();   // all Xs reads done before A-combine aliases over it

  // ---- phase 5: cross-wave A' combine into LDS (aliases dead Xs region)
  float* Ac = (float*)&Xs[0][0];   // 8*512 f32 = 16 KB
  {
    const int j0 = lane * 4, j1 = j0 + 256;
    for (int wv = 0; wv < 4; ++wv) {
      if (w == wv) {
#pragma unroll
        for (int hh = 0; hh < 8; ++hh) {
          float4* p0 = (float4*)&Ac[hh * 512 + j0];
          float4* p1 = (float4*)&Ac[hh * 512 + j1];
          const float4 a0 = make_float4(A2[hh][0][0], A2[hh][0][1],
                                        A2[hh][1][0], A2[hh][1][1]);
          const float4 a1 = make_float4(A2[hh][2][0], A2[hh][2][1],
                                        A2[hh][3][0], A2[hh][3][1]);
          if (wv == 0) { *p0 = a0; *p1 = a1; }
          else {
            float4 v0 = *p0, v1 = *p1;
            v0.x += a0.x; v0.y += a0.y; v0.z += a0.z; v0.w += a0.w;
            v1.x += a1.x; v1.y += a1.y; v1.z += a1.z; v1.w += a1.w;
            *p0 = v0; *p1 = v1;
          }
        }
      }
      __syncthreads();
    }
  }

  if (tid < 8) {
    float Bt = 0.f, Lt = 0.f;
    for (int wv = 0; wv < 4; ++wv) { Bt += wstatB[wv][tid]; Lt += wstatL[wv][tid]; }
    float den = Lt;
#pragma unroll
    for (int k = 0; k < 5; ++k) {
      const float e = __expf(sc2_s[tid][k]);
      e2_s[tid][k] = e; den += e;
    }
    Bt_s[tid] = Bt; Lt_s[tid] = Lt; inv_s[tid] = 1.f / den;
  }
  __syncthreads();

  // ---- epilogue: u[h][j] (bf16) = (A' - B*g + L*b + sum e2*h2) / den
  __hip_bfloat16* dst = u_out + (size_t)n * 4096;
  for (int bidx = tid * 4; bidx < 4096; bidx += 1024) {
    const int hh = bidx >> 9, j = bidx & 511;
    const float4 a4 = *(const float4*)&Ac[hh * 512 + j];
    const float4 g4 = *(const float4*)&g_s[j];
    const float4 b4 = *(const float4*)&b_s[j];
    const float Bt = Bt_s[hh], Lt = Lt_s[hh];
    float v0 = a4.x - Bt * g4.x + Lt * b4.x;
    float v1 = a4.y - Bt * g4.y + Lt * b4.y;
    float v2 = a4.z - Bt * g4.z + Lt * b4.z;
    float v3 = a4.w - Bt * g4.w + Lt * b4.w;
#pragma unroll
    for (int k = 0; k < 5; ++k) {
      const s16x4 hq = *(const s16x4*)&h2_s[k][j];
      const float e = e2_s[hh][k];
      v0 += e * bfs2f(hq[0]); v1 += e * bfs2f(hq[1]);
      v2 += e * bfs2f(hq[2]); v3 += e * bfs2f(hq[3]);
    }
    const float iv = inv_s[hh];
    s16x4 o;
    o[0] = f2bf(v0 * iv); o[1] = f2bf(v1 * iv);
    o[2] = f2bf(v2 * iv); o[3] = f2bf(v3 * iv);
    *(s16x4*)&dst[bidx] = o;
  }
}

// ---------------------------------------------------------------------------
extern "C" void kernel_launch(void* const* d_in, const int* in_sizes, int n_in,
                              void* d_out, int out_size, void* d_ws, size_t ws_size,
                              hipStream_t stream)
{
  const float* images = (const float*)d_in[0];
  const float* W_img  = (const float*)d_in[1];
  const float* ctx    = (const float*)d_in[2];
  const float* cls    = (const float*)d_in[3];
  const float* ln_g   = (const float*)d_in[4];
  const float* ln_b   = (const float*)d_in[5];
  const float* Wq     = (const float*)d_in[6];
  const float* Wk     = (const float*)d_in[7];
  const float* Wv     = (const float*)d_in[8];
  const float* Wo     = (const float*)d_in[9];
  const float* tproj  = (const float*)d_in[10];
  const float* lscale = (const float*)d_in[11];

  __hip_bfloat16* wtu = (__hip_bfloat16*)d_ws;  // wt -> u (bf16, in place)
  float* fws  = (float*)d_ws;
  float* img  = fws + 2048000;
  float* hlO  = img + 131072;       // O
  float* qo2  = hlO + 512000;       // q -> out2
  float* txt  = fws;                // alias over dead u region
  (void)in_sizes; (void)n_in; (void)out_size; (void)ws_size;

  // 1) image embedding (bf16 MFMA), unnormalized (logits_k normalizes)
  gemm_mfma_k<0,0,0,0><<<dim3(8,4,1),256,0,stream>>>(images,768,0, W_img,512,0,
      img,512,0, nullptr,0, 256,512,768);

  // 2) q = LN(cls_last) @ Wq  (LN fused into staging)
  gemm_mfma_lnA_k<<<dim3(8,16),256,0,stream>>>(cls + 71*512, 72*512,
      ln_g, ln_b, Wq,512, qo2,512, 1000,512,512);

  // 3) wt = per-head q @ Wk^T  -> bf16
  gemm_mfma_k<1,0,0,1><<<dim3(8,16,8),256,0,stream>>>(qo2,512,64, Wk,512,64,
      wtu,4096,512, nullptr,0, 1000,512,64);

  // 4+5) fused pass1+pass2 sweep (MFMA scores) -> u bf16 (in place over wt)
  fused_sweep_kernel<<<1000,256,0,stream>>>(ctx, cls, ln_g, ln_b, wtu, wtu);

  // 6) O = per-head u @ Wv  (A read directly as bf16)
  gemm_mfma_k<0,0,1,0><<<dim3(1,16,8),256,0,stream>>>(wtu,4096,512, Wv,512,64,
      hlO,512,64, nullptr,0, 1000,64,512);

  // 7) out2 = cls_last + O @ Wo ; txt = out2 @ text_proj  (bf16 MFMA)
  gemm_mfma_k<0,1,0,0><<<dim3(8,16,1),256,0,stream>>>(hlO,512,0, Wo,512,0,
      qo2,512,0, cls + 71*512, 72*512, 1000,512,512);
  gemm_mfma_k<0,0,0,0><<<dim3(8,16,1),256,0,stream>>>(qo2,512,0, tproj,512,0,
      txt,512,0, nullptr,0, 1000,512,512);

  // 8) logits = exp(ls) * (img/|img|) @ (txt/|txt|)^T  (norms fused, f32)
  logits_k<<<dim3(16,8),256,0,stream>>>(img,512, txt,512,
      (float*)d_out,1000, lscale, 256,1000,512);
}

// Round 15
// 153.761 us; speedup vs baseline: 1.1397x; 1.1397x over previous
//
#include <hip/hip_runtime.h>
#include <hip/hip_bf16.h>

#define DEV static __device__ __forceinline__

typedef __attribute__((ext_vector_type(8))) short bf16x8;
typedef __attribute__((ext_vector_type(4))) short s16x4;
typedef __attribute__((ext_vector_type(4))) float f32x4;
typedef __attribute__((ext_vector_type(2))) float f32x2;

DEV float wsum(float v) {
  v += __shfl_xor(v, 1);  v += __shfl_xor(v, 2);  v += __shfl_xor(v, 4);
  v += __shfl_xor(v, 8);  v += __shfl_xor(v, 16); v += __shfl_xor(v, 32);
  return v;
}
DEV float wmaxr(float v) {
  v = fmaxf(v, __shfl_xor(v, 1));  v = fmaxf(v, __shfl_xor(v, 2));
  v = fmaxf(v, __shfl_xor(v, 4));  v = fmaxf(v, __shfl_xor(v, 8));
  v = fmaxf(v, __shfl_xor(v, 16)); v = fmaxf(v, __shfl_xor(v, 32));
  return v;
}
DEV short f2bf(float x) {
  __hip_bfloat16 h = __float2bfloat16(x);
  return *reinterpret_cast<short*>(&h);
}
DEV float bf2f(unsigned int u) {
  const unsigned int x = u << 16;
  return __uint_as_float(x);
}
DEV float bfs2f(short s) {
  const unsigned int x = ((unsigned int)(unsigned short)s) << 16;
  return __uint_as_float(x);
}
DEV void split4(const float4& v, f32x2& lo, f32x2& hi) {
  lo = f32x2{v.x, v.y}; hi = f32x2{v.z, v.w};
}

// Fold-reduce 8 per-lane values across 64 lanes -> full sum of head (lane&7).
DEV float fold8(const float v[8], int lane) {
  float w4[4];
#pragma unroll
  for (int j = 0; j < 4; ++j) {
    const float mine  = (lane & 1) ? v[2 * j + 1] : v[2 * j];
    const float other = (lane & 1) ? v[2 * j]     : v[2 * j + 1];
    w4[j] = mine + __shfl_xor(other, 1);
  }
  float u2[2];
#pragma unroll
  for (int j = 0; j < 2; ++j) {
    const float mine  = (lane & 2) ? w4[2 * j + 1] : w4[2 * j];
    const float other = (lane & 2) ? w4[2 * j]     : w4[2 * j + 1];
    u2[j] = mine + __shfl_xor(other, 2);
  }
  const float mine  = (lane & 4) ? u2[1] : u2[0];
  const float other = (lane & 4) ? u2[0] : u2[1];
  float z = mine + __shfl_xor(other, 4);
  z += __shfl_xor(z, 8); z += __shfl_xor(z, 16); z += __shfl_xor(z, 32);
  return z;
}

// ---------------------------------------------------------------------------
// Unified bf16 MFMA GEMM: depth-2 register prefetch + LDS double buffer.
// (HW-validated rounds 12/13)
// ---------------------------------------------------------------------------
template <int TRANSB, int ADDD, int ABF16, int OUTBF16>
__global__ __launch_bounds__(256) void gemm_mfma_k(
    const void* __restrict__ Av, int lda, long long bsA,
    const float* __restrict__ B, int ldb, long long bsB,
    void* __restrict__ Cv, int ldc, long long bsC,
    const float* __restrict__ D, long long ldd,
    int M, int N, int K)
{
  const float* Af = (const float*)Av + (ABF16 ? 0 : (size_t)blockIdx.z * bsA);
  const short* Ah = (const short*)Av + (ABF16 ? (size_t)blockIdx.z * bsA : 0);
  B += (size_t)blockIdx.z * bsB;
  const int m0 = blockIdx.y * 64, n0 = blockIdx.x * 64;
  const int tid = threadIdx.x;
  const int w = tid >> 6, lane = tid & 63;
  const int wr = w >> 1, wc = w & 1;
  __shared__ __attribute__((aligned(16))) short As[2][64][40];
  __shared__ __attribute__((aligned(16))) short Bs[2][64][40];
  f32x4 acc[2][2] = {};

  const int ar = tid >> 2, akc = (tid & 3) * 8;
  const int br = tid >> 3, bnc = (tid & 7) * 8;
  const bool arv = (m0 + ar < M);
  const int rbase = wr * 32 + (lane & 15);
  const int cbase = wc * 32 + (lane & 15);
  const int kb = (lane >> 4) * 8;

  auto gload = [&](int k0, float4& a0, float4& a1, bf16x8& ah,
                   float4& b0, float4& b1) {
    if (ABF16) {
      ah = bf16x8{};
      if (arv) ah = *(const bf16x8*)(Ah + (size_t)(m0 + ar) * lda + k0 + akc);
    } else {
      a0 = make_float4(0.f, 0.f, 0.f, 0.f); a1 = a0;
      if (arv) {
        a0 = *(const float4*)(Af + (size_t)(m0 + ar) * lda + k0 + akc);
        a1 = *(const float4*)(Af + (size_t)(m0 + ar) * lda + k0 + akc + 4);
      }
    }
    if (TRANSB) {
      b0 = *(const float4*)(B + (size_t)(n0 + ar) * ldb + k0 + akc);
      b1 = *(const float4*)(B + (size_t)(n0 + ar) * ldb + k0 + akc + 4);
    } else {
      b0 = *(const float4*)(B + (size_t)(k0 + br) * ldb + n0 + bnc);
      b1 = *(const float4*)(B + (size_t)(k0 + br) * ldb + n0 + bnc + 4);
    }
  };
  auto stage = [&](int buf, const float4& a0, const float4& a1, const bf16x8& ah,
                   const float4& b0, const float4& b1) {
    if (ABF16) {
      *(bf16x8*)&As[buf][ar][akc] = ah;
    } else {
      bf16x8 av;
      av[0] = f2bf(a0.x); av[1] = f2bf(a0.y); av[2] = f2bf(a0.z); av[3] = f2bf(a0.w);
      av[4] = f2bf(a1.x); av[5] = f2bf(a1.y); av[6] = f2bf(a1.z); av[7] = f2bf(a1.w);
      *(bf16x8*)&As[buf][ar][akc] = av;
    }
    if (TRANSB) {
      bf16x8 bv;
      bv[0] = f2bf(b0.x); bv[1] = f2bf(b0.y); bv[2] = f2bf(b0.z); bv[3] = f2bf(b0.w);
      bv[4] = f2bf(b1.x); bv[5] = f2bf(b1.y); bv[6] = f2bf(b1.z); bv[7] = f2bf(b1.w);
      *(bf16x8*)&Bs[buf][ar][akc] = bv;
    } else {
      Bs[buf][bnc + 0][br] = f2bf(b0.x); Bs[buf][bnc + 1][br] = f2bf(b0.y);
      Bs[buf][bnc + 2][br] = f2bf(b0.z); Bs[buf][bnc + 3][br] = f2bf(b0.w);
      Bs[buf][bnc + 4][br] = f2bf(b1.x); Bs[buf][bnc + 5][br] = f2bf(b1.y);
      Bs[buf][bnc + 6][br] = f2bf(b1.z); Bs[buf][bnc + 7][br] = f2bf(b1.w);
    }
  };
  auto compute = [&](int buf) {
    bf16x8 af0 = *(const bf16x8*)&As[buf][rbase][kb];
    bf16x8 af1 = *(const bf16x8*)&As[buf][rbase + 16][kb];
    bf16x8 bf0 = *(const bf16x8*)&Bs[buf][cbase][kb];
    bf16x8 bf1 = *(const bf16x8*)&Bs[buf][cbase + 16][kb];
    acc[0][0] = __builtin_amdgcn_mfma_f32_16x16x32_bf16(af0, bf0, acc[0][0], 0, 0, 0);
    acc[0][1] = __builtin_amdgcn_mfma_f32_16x16x32_bf16(af0, bf1, acc[0][1], 0, 0, 0);
    acc[1][0] = __builtin_amdgcn_mfma_f32_16x16x32_bf16(af1, bf0, acc[1][0], 0, 0, 0);
    acc[1][1] = __builtin_amdgcn_mfma_f32_16x16x32_bf16(af1, bf1, acc[1][1], 0, 0, 0);
  };

  float4 a0A, a1A, b0A, b1A, a0B, a1B, b0B, b1B;
  bf16x8 ahA = {}, ahB = {};
  gload(0, a0A, a1A, ahA, b0A, b1A);
  gload(32, a0B, a1B, ahB, b0B, b1B);
  for (int k0 = 0; k0 < K; k0 += 64) {
    stage(0, a0A, a1A, ahA, b0A, b1A);
    if (k0 + 64 < K) gload(k0 + 64, a0A, a1A, ahA, b0A, b1A);
    __syncthreads();
    compute(0);
    stage(1, a0B, a1B, ahB, b0B, b1B);
    if (k0 + 96 < K) gload(k0 + 96, a0B, a1B, ahB, b0B, b1B);
    __syncthreads();
    compute(1);
  }

  const size_t cb = (size_t)blockIdx.z * (size_t)bsC;
#pragma unroll
  for (int mi = 0; mi < 2; ++mi)
#pragma unroll
    for (int ni = 0; ni < 2; ++ni)
#pragma unroll
      for (int r = 0; r < 4; ++r) {
        const int row = m0 + wr * 32 + mi * 16 + (lane >> 4) * 4 + r;
        const int col = n0 + wc * 32 + ni * 16 + (lane & 15);
        if (row < M) {
          float v = acc[mi][ni][r];
          if (ADDD) v += D[(size_t)row * ldd + col];
          if (OUTBF16)
            ((__hip_bfloat16*)Cv)[cb + (size_t)row * ldc + col] = __float2bfloat16(v);
          else
            ((float*)Cv)[cb + (size_t)row * ldc + col] = v;
        }
      }
}

// ---------------------------------------------------------------------------
// bf16 MFMA GEMM with LayerNorm fused on A (unchanged).
// ---------------------------------------------------------------------------
__global__ __launch_bounds__(256) void gemm_mfma_lnA_k(
    const float* __restrict__ A, long long lda,
    const float* __restrict__ g, const float* __restrict__ b,
    const float* __restrict__ B, int ldb,
    float* __restrict__ C, int ldc,
    int M, int N, int K)
{
  const int m0 = blockIdx.y * 64, n0 = blockIdx.x * 64;
  const int tid = threadIdx.x;
  const int w = tid >> 6, lane = tid & 63;
  const int wr = w >> 1, wc = w & 1;
  __shared__ __attribute__((aligned(16))) short As[2][64][40];
  __shared__ __attribute__((aligned(16))) short Bs[2][64][40];
  __shared__ __attribute__((aligned(16))) float g_s[512], b_s[512];
  __shared__ float mean_s[64], rstd_s[64];
  f32x4 acc[2][2] = {};

  if (tid < 128) ((float4*)g_s)[tid] = ((const float4*)g)[tid];
  else ((float4*)b_s)[tid - 128] = ((const float4*)b)[tid - 128];

  {
    const int r = tid >> 2, p = tid & 3;
    float s = 0.f, ss = 0.f;
    if (m0 + r < M) {
      const float4* src = (const float4*)(A + (size_t)(m0 + r) * lda + p * 128);
#pragma unroll 8
      for (int i = 0; i < 32; ++i) {
        const float4 v = src[i];
        s += v.x + v.y + v.z + v.w;
        ss += v.x * v.x + v.y * v.y + v.z * v.z + v.w * v.w;
      }
    }
    s += __shfl_xor(s, 1);  s += __shfl_xor(s, 2);
    ss += __shfl_xor(ss, 1); ss += __shfl_xor(ss, 2);
    if (p == 0) {
      const float mean = s * (1.f / 512.f);
      mean_s[r] = mean;
      rstd_s[r] = rsqrtf(ss * (1.f / 512.f) - mean * mean + 1e-5f);
    }
  }
  __syncthreads();

  const int ar = tid >> 2, akc = (tid & 3) * 8;
  const int br = tid >> 3, bnc = (tid & 7) * 8;
  const bool arv = (m0 + ar < M);
  const int rbase = wr * 32 + (lane & 15);
  const int cbase = wc * 32 + (lane & 15);
  const int kb = (lane >> 4) * 8;

  auto gload = [&](int k0, float4& a0, float4& a1, float4& b0, float4& b1) {
    a0 = make_float4(0.f, 0.f, 0.f, 0.f); a1 = a0;
    if (arv) {
      a0 = *(const float4*)(A + (size_t)(m0 + ar) * lda + k0 + akc);
      a1 = *(const float4*)(A + (size_t)(m0 + ar) * lda + k0 + akc + 4);
    }
    b0 = *(const float4*)(B + (size_t)(k0 + br) * ldb + n0 + bnc);
    b1 = *(const float4*)(B + (size_t)(k0 + br) * ldb + n0 + bnc + 4);
  };
  auto stage = [&](int buf, int k0, const float4& a0, const float4& a1,
                   const float4& b0, const float4& b1) {
    const float mn = mean_s[ar], rs = rstd_s[ar];
    const int kc = k0 + akc;
    bf16x8 av;
    av[0] = f2bf((a0.x - mn) * rs * g_s[kc + 0] + b_s[kc + 0]);
    av[1] = f2bf((a0.y - mn) * rs * g_s[kc + 1] + b_s[kc + 1]);
    av[2] = f2bf((a0.z - mn) * rs * g_s[kc + 2] + b_s[kc + 2]);
    av[3] = f2bf((a0.w - mn) * rs * g_s[kc + 3] + b_s[kc + 3]);
    av[4] = f2bf((a1.x - mn) * rs * g_s[kc + 4] + b_s[kc + 4]);
    av[5] = f2bf((a1.y - mn) * rs * g_s[kc + 5] + b_s[kc + 5]);
    av[6] = f2bf((a1.z - mn) * rs * g_s[kc + 6] + b_s[kc + 6]);
    av[7] = f2bf((a1.w - mn) * rs * g_s[kc + 7] + b_s[kc + 7]);
    *(bf16x8*)&As[buf][ar][akc] = av;
    Bs[buf][bnc + 0][br] = f2bf(b0.x); Bs[buf][bnc + 1][br] = f2bf(b0.y);
    Bs[buf][bnc + 2][br] = f2bf(b0.z); Bs[buf][bnc + 3][br] = f2bf(b0.w);
    Bs[buf][bnc + 4][br] = f2bf(b1.x); Bs[buf][bnc + 5][br] = f2bf(b1.y);
    Bs[buf][bnc + 6][br] = f2bf(b1.z); Bs[buf][bnc + 7][br] = f2bf(b1.w);
  };
  auto compute = [&](int buf) {
    bf16x8 af0 = *(const bf16x8*)&As[buf][rbase][kb];
    bf16x8 af1 = *(const bf16x8*)&As[buf][rbase + 16][kb];
    bf16x8 bf0 = *(const bf16x8*)&Bs[buf][cbase][kb];
    bf16x8 bf1 = *(const bf16x8*)&Bs[buf][cbase + 16][kb];
    acc[0][0] = __builtin_amdgcn_mfma_f32_16x16x32_bf16(af0, bf0, acc[0][0], 0, 0, 0);
    acc[0][1] = __builtin_amdgcn_mfma_f32_16x16x32_bf16(af0, bf1, acc[0][1], 0, 0, 0);
    acc[1][0] = __builtin_amdgcn_mfma_f32_16x16x32_bf16(af1, bf0, acc[1][0], 0, 0, 0);
    acc[1][1] = __builtin_amdgcn_mfma_f32_16x16x32_bf16(af1, bf1, acc[1][1], 0, 0, 0);
  };

  float4 a0A, a1A, b0A, b1A, a0B, a1B, b0B, b1B;
  gload(0, a0A, a1A, b0A, b1A);
  gload(32, a0B, a1B, b0B, b1B);
  for (int k0 = 0; k0 < K; k0 += 64) {
    stage(0, k0, a0A, a1A, b0A, b1A);
    if (k0 + 64 < K) gload(k0 + 64, a0A, a1A, b0A, b1A);
    __syncthreads();
    compute(0);
    stage(1, k0 + 32, a0B, a1B, b0B, b1B);
    if (k0 + 96 < K) gload(k0 + 96, a0B, a1B, b0B, b1B);
    __syncthreads();
    compute(1);
  }

#pragma unroll
  for (int mi = 0; mi < 2; ++mi)
#pragma unroll
    for (int ni = 0; ni < 2; ++ni)
#pragma unroll
      for (int r = 0; r < 4; ++r) {
        const int row = m0 + wr * 32 + mi * 16 + (lane >> 4) * 4 + r;
        const int col = n0 + wc * 32 + ni * 16 + (lane & 15);
        if (row < M) C[(size_t)row * ldc + col] = acc[mi][ni][r];
      }
}

// ---------------------------------------------------------------------------
// Logits GEMM with fused L2 norms (unchanged).
// ---------------------------------------------------------------------------
__global__ __launch_bounds__(256) void logits_k(
    const float* __restrict__ A, int lda,
    const float* __restrict__ B, int ldb,
    float* __restrict__ C, int ldc,
    const float* __restrict__ alpha_ptr,
    int M, int N, int K)
{
  const int m0 = blockIdx.y * 32, n0 = blockIdx.x * 64;
  const int tid = threadIdx.x;
  __shared__ __attribute__((aligned(16))) float As[2][16][36];
  __shared__ __attribute__((aligned(16))) float Bs[2][16][68];
  __shared__ float nA[32], nB[64];
  float acc[2][4] = {};
  float ssA = 0.f, ssB = 0.f;
  const int ty = tid >> 4, tx = tid & 15;
  const int am = tid >> 3, ak = (tid & 7) * 2;
  const int bm = tid >> 2, bt = (tid & 3) * 4;
  const bool aval = (m0 + am < M);
  const bool bval = (n0 + bm < N);

  float2 av; float4 bv;
  auto gload = [&](int k0) {
    av = make_float2(0.f, 0.f);
    bv = make_float4(0.f, 0.f, 0.f, 0.f);
    if (aval) av = *(const float2*)(A + (size_t)(m0 + am) * lda + (k0 + ak));
    if (bval) bv = *(const float4*)(B + (size_t)(n0 + bm) * ldb + (k0 + bt));
    ssA += av.x * av.x + av.y * av.y;
    ssB += bv.x * bv.x + bv.y * bv.y + bv.z * bv.z + bv.w * bv.w;
  };
  auto sstore = [&](int buf) {
    As[buf][ak][am] = av.x; As[buf][ak + 1][am] = av.y;
    Bs[buf][bt + 0][bm] = bv.x; Bs[buf][bt + 1][bm] = bv.y;
    Bs[buf][bt + 2][bm] = bv.z; Bs[buf][bt + 3][bm] = bv.w;
  };

  const int nIt = K >> 4;
  gload(0); sstore(0);
  for (int it = 0; it < nIt; ++it) {
    __syncthreads();
    if (it + 1 < nIt) gload((it + 1) << 4);
    const int buf = it & 1;
#pragma unroll
    for (int kk = 0; kk < 16; ++kk) {
      const float2 a  = *(const float2*)&As[buf][kk][ty * 2];
      const float4 bq = *(const float4*)&Bs[buf][kk][tx * 4];
      acc[0][0] += a.x * bq.x; acc[0][1] += a.x * bq.y; acc[0][2] += a.x * bq.z; acc[0][3] += a.x * bq.w;
      acc[1][0] += a.y * bq.x; acc[1][1] += a.y * bq.y; acc[1][2] += a.y * bq.z; acc[1][3] += a.y * bq.w;
    }
    if (it + 1 < nIt) sstore((it + 1) & 1);
  }

  ssA += __shfl_xor(ssA, 1); ssA += __shfl_xor(ssA, 2); ssA += __shfl_xor(ssA, 4);
  if ((tid & 7) == 0) nA[am] = rsqrtf(ssA);
  ssB += __shfl_xor(ssB, 1); ssB += __shfl_xor(ssB, 2);
  if ((tid & 3) == 0) nB[bm] = rsqrtf(ssB);
  __syncthreads();

  const float alpha = __expf(alpha_ptr[0]);
#pragma unroll
  for (int i = 0; i < 2; ++i) {
    const int m = m0 + ty * 2 + i;
    if (m >= M) continue;
    const float fa = alpha * nA[ty * 2 + i];
#pragma unroll
    for (int j = 0; j < 4; ++j) {
      const int nn = n0 + tx * 4 + j;
      if (nn < N) C[(size_t)m * ldc + nn] = acc[i][j] * fa * nB[tx * 4 + j];
    }
  }
}

// ---------------------------------------------------------------------------
// FUSED sweep v8 (round-13 state — best known-good, 90 us).
// ---------------------------------------------------------------------------
__global__ __launch_bounds__(256) void fused_sweep_kernel(
    const float* __restrict__ ctx, const float* __restrict__ cls,
    const float* __restrict__ g, const float* __restrict__ b,
    const __hip_bfloat16* __restrict__ wt, __hip_bfloat16* __restrict__ u_out)
{
  const int n = blockIdx.x, tid = threadIdx.x;
  const int w = tid >> 6, lane = tid & 63;
  __shared__ __attribute__((aligned(16))) float gw_s[8][512];
  __shared__ __attribute__((aligned(16))) float g_s[512], b_s[512];
  __shared__ __attribute__((aligned(16))) short h2_s[5][512];   // bf16 h2
  __shared__ float sc_s[8][80];
  __shared__ float sc2_s[8][5];
  __shared__ float ah_s[8][5];
  __shared__ float wstatB[4][8], wstatL[4][8];
  __shared__ float attr_s[5];
  __shared__ float Sgw_l[8], bw_l[8];
  __shared__ float Bt_s[8], Lt_s[8], inv_s[8];
  __shared__ float e2_s[8][5];
  __shared__ __attribute__((aligned(16))) float es_s[4][2][8];

  {
    const uint4* wsrc = (const uint4*)(wt + (size_t)n * 4096);
    float4* gwf = (float4*)&gw_s[0][0];
    for (int i = tid; i < 512; i += 256) {
      const uint4 v = wsrc[i];
      gwf[i * 2]     = make_float4(bf2f(v.x & 0xffffu), bf2f(v.x >> 16),
                                   bf2f(v.y & 0xffffu), bf2f(v.y >> 16));
      gwf[i * 2 + 1] = make_float4(bf2f(v.z & 0xffffu), bf2f(v.z >> 16),
                                   bf2f(v.w & 0xffffu), bf2f(v.w >> 16));
    }
    if (tid < 128) ((float4*)g_s)[tid] = ((const float4*)g)[tid];
    else ((float4*)b_s)[tid - 128] = ((const float4*)b)[tid - 128];
  }
  __syncthreads();

  for (int hh = w; hh < 8; hh += 4) {
    float s1 = 0.f, s2 = 0.f;
#pragma unroll
    for (int i = 0; i < 8; ++i) {
      const int j = lane + 64 * i;
      const float wv = gw_s[hh][j];
      const float gv = wv * g_s[j];
      s1 += gv; s2 += wv * b_s[j];
      gw_s[hh][j] = gv;
    }
    s1 = wsum(s1); s2 = wsum(s2);
    if (lane == 0) { Sgw_l[hh] = s1; bw_l[hh] = s2; }
  }
  __syncthreads();
  const float sg_r  = Sgw_l[lane & 7];
  const float bw8_r = bw_l[lane & 7] * 0.125f;
  const int j0 = lane * 4, j1 = lane * 4 + 256;

  // ---- stage A: 5 unscaled ctx rows (global reads) -> pass-1 scores
  for (int k = w; k < 5; k += 4) {
    const float* src = ctx + ((size_t)n * 5 + k) * 512;
    const float4 x0 = *(const float4*)(src + j0);
    const float4 x1 = *(const float4*)(src + j1);
    f32x2 q[4];
    split4(x0, q[0], q[1]); split4(x1, q[2], q[3]);
    f32x2 s2v = q[0] + q[1] + q[2] + q[3];
    f32x2 ss2 = q[0] * q[0] + q[1] * q[1] + q[2] * q[2] + q[3] * q[3];
    float s  = s2v[0] + s2v[1];
    float ss = ss2[0] + ss2[1];
    float v8[8];
#pragma unroll
    for (int hh = 0; hh < 8; ++hh) {
      const float4 w0 = *(const float4*)&gw_s[hh][j0];
      const float4 w1 = *(const float4*)&gw_s[hh][j1];
      f32x2 g0, g1, g2, g3;
      split4(w0, g0, g1); split4(w1, g2, g3);
      f32x2 d = q[0] * g0 + q[1] * g1 + q[2] * g2 + q[3] * g3;
      v8[hh] = d[0] + d[1];
    }
    s = wsum(s); ss = wsum(ss);
    const float mean = s * (1.f / 512.f);
    const float rstd = rsqrtf(ss * (1.f / 512.f) - mean * mean + 1e-5f);
    const float z = fold8(v8, lane);
    const float zf = rstd * 0.125f * (z - mean * sg_r) + bw8_r;
    if (lane < 8) sc_s[lane][k] = zf;
  }

  // ---- stage B: 72 cls rows, 9 pairs/wave, prefetch depth 2, f32x2 math
  f32x2 A2[8][4];
#pragma unroll
  for (int hh = 0; hh < 8; ++hh)
#pragma unroll
    for (int i = 0; i < 4; ++i) A2[hh][i] = f32x2{0.f, 0.f};
  float B8[8] = {}, L8[8] = {};

  const float* base = cls + (size_t)n * 72 * 512;
  float4 xa0, xa1, xb0, xb1, ya0, ya1, yb0, yb1;
  {
    const float* sA = base + (size_t)w * 512;
    const float* sB = base + (size_t)(w + 4) * 512;
    xa0 = *(const float4*)(sA + j0); xa1 = *(const float4*)(sA + j1);
    xb0 = *(const float4*)(sB + j0); xb1 = *(const float4*)(sB + j1);
    const float* sA1 = base + (size_t)(w + 8) * 512;
    const float* sB1 = base + (size_t)(w + 12) * 512;
    ya0 = *(const float4*)(sA1 + j0); ya1 = *(const float4*)(sA1 + j1);
    yb0 = *(const float4*)(sB1 + j0); yb1 = *(const float4*)(sB1 + j1);
  }
  for (int p = 0; p < 9; ++p) {
    float4 za0, za1, zb0, zb1;
    const bool more2 = (p + 2 < 9);
    if (more2) {
      const float* sA = base + (size_t)(w + 8 * (p + 2)) * 512;
      const float* sB = base + (size_t)(w + 4 + 8 * (p + 2)) * 512;
      za0 = *(const float4*)(sA + j0); za1 = *(const float4*)(sA + j1);
      zb0 = *(const float4*)(sB + j0); zb1 = *(const float4*)(sB + j1);
    }
    f32x2 qa[4], qb[4];
    split4(xa0, qa[0], qa[1]); split4(xa1, qa[2], qa[3]);
    split4(xb0, qb[0], qb[1]); split4(xb1, qb[2], qb[3]);
    f32x2 sa2 = qa[0] + qa[1] + qa[2] + qa[3];
    f32x2 ssa2 = qa[0] * qa[0] + qa[1] * qa[1] + qa[2] * qa[2] + qa[3] * qa[3];
    f32x2 sb2 = qb[0] + qb[1] + qb[2] + qb[3];
    f32x2 ssb2 = qb[0] * qb[0] + qb[1] * qb[1] + qb[2] * qb[2] + qb[3] * qb[3];
    float sa = sa2[0] + sa2[1], ssa = ssa2[0] + ssa2[1];
    float sb = sb2[0] + sb2[1], ssb = ssb2[0] + ssb2[1];
    float v8a[8], v8b[8];
#pragma unroll
    for (int hh = 0; hh < 8; ++hh) {
      const float4 w0 = *(const float4*)&gw_s[hh][j0];
      const float4 w1 = *(const float4*)&gw_s[hh][j1];
      f32x2 g0, g1, g2, g3;
      split4(w0, g0, g1); split4(w1, g2, g3);
      f32x2 da = qa[0] * g0 + qa[1] * g1 + qa[2] * g2 + qa[3] * g3;
      f32x2 db = qb[0] * g0 + qb[1] * g1 + qb[2] * g2 + qb[3] * g3;
      v8a[hh] = da[0] + da[1];
      v8b[hh] = db[0] + db[1];
    }
    sa = wsum(sa); ssa = wsum(ssa); sb = wsum(sb); ssb = wsum(ssb);
    const float meanA = sa * (1.f / 512.f);
    const float rstdA = rsqrtf(ssa * (1.f / 512.f) - meanA * meanA + 1e-5f);
    const float meanB = sb * (1.f / 512.f);
    const float rstdB = rsqrtf(ssb * (1.f / 512.f) - meanB * meanB + 1e-5f);
    const float za = fold8(v8a, lane);
    const float zb = fold8(v8b, lane);
    const float zfa = rstdA * 0.125f * (za - meanA * sg_r) + bw8_r;
    const float zfb = rstdB * 0.125f * (zb - meanB * sg_r) + bw8_r;
    const int kA = 5 + w + 8 * p;
    if (lane < 8) {
      sc_s[lane][kA] = zfa; sc_s[lane][kA + 4] = zfb;
      es_s[w][0][lane] = __expf(zfa);
      es_s[w][1][lane] = __expf(zfb);
    }
    __builtin_amdgcn_wave_barrier();
    const float4 ea0 = *(const float4*)&es_s[w][0][0];
    const float4 ea1 = *(const float4*)&es_s[w][0][4];
    const float4 eb0 = *(const float4*)&es_s[w][1][0];
    const float4 eb1 = *(const float4*)&es_s[w][1][4];
    const float esa[8] = {ea0.x, ea0.y, ea0.z, ea0.w, ea1.x, ea1.y, ea1.z, ea1.w};
    const float esb[8] = {eb0.x, eb0.y, eb0.z, eb0.w, eb1.x, eb1.y, eb1.z, eb1.w};
#pragma unroll
    for (int hh = 0; hh < 8; ++hh) {
      const float erA = esa[hh] * rstdA;
      const float erB = esb[hh] * rstdB;
      const f32x2 eA = f32x2{erA, erA};
      const f32x2 eB = f32x2{erB, erB};
      A2[hh][0] += eA * qa[0]; A2[hh][1] += eA * qa[1];
      A2[hh][2] += eA * qa[2]; A2[hh][3] += eA * qa[3];
      A2[hh][0] += eB * qb[0]; A2[hh][1] += eB * qb[1];
      A2[hh][2] += eB * qb[2]; A2[hh][3] += eB * qb[3];
      B8[hh] += erA * meanA + erB * meanB;
      L8[hh] += esa[hh] + esb[hh];
    }
    xa0 = ya0; xa1 = ya1; xb0 = yb0; xb1 = yb1;
    if (more2) { ya0 = za0; ya1 = za1; yb0 = zb0; yb1 = zb1; }
  }
  if (lane == 0)
#pragma unroll
    for (int hh = 0; hh < 8; ++hh) {
      wstatB[w][hh] = B8[hh]; wstatL[w][hh] = L8[hh];
    }
  __syncthreads();

  // ---- pass-1 softmax over 77 -> head-mean of first 5 -> attr
  for (int hh = w; hh < 8; hh += 4) {
    const float v0 = sc_s[hh][lane];
    const float v1 = (lane + 64 < 77) ? sc_s[hh][lane + 64] : -1e30f;
    const float mx = wmaxr(fmaxf(v0, v1));
    const float e0 = __expf(v0 - mx);
    const float e1 = (lane + 64 < 77) ? __expf(v1 - mx) : 0.f;
    const float S = wsum(e0 + e1);
    if (lane < 5) ah_s[hh][lane] = e0 / S;
  }
  __syncthreads();
  if (tid == 0) {
    float m[5], mx = -1e30f;
#pragma unroll
    for (int p = 0; p < 5; ++p) {
      float acc = 0.f;
      for (int hh = 0; hh < 8; ++hh) acc += ah_s[hh][p];
      m[p] = acc * 0.125f;
      mx = fmaxf(mx, m[p]);
    }
    float e[5], S = 0.f;
#pragma unroll
    for (int p = 0; p < 5; ++p) { e[p] = __expf(m[p] - mx); S += e[p]; }
#pragma unroll
    for (int p = 0; p < 5; ++p) attr_s[p] = e[p] / S;
  }
  __syncthreads();

  // ---- stage C: scaled ctx rows (global reads) -> h2 (bf16 LDS) + sc2
  for (int k = w; k < 5; k += 4) {
    const float c = attr_s[k];
    const float* src = ctx + ((size_t)n * 5 + k) * 512;
    float4 x0 = *(const float4*)(src + j0);
    float4 x1 = *(const float4*)(src + j1);
    x0.x *= c; x0.y *= c; x0.z *= c; x0.w *= c;
    x1.x *= c; x1.y *= c; x1.z *= c; x1.w *= c;
    f32x2 q[4];
    split4(x0, q[0], q[1]); split4(x1, q[2], q[3]);
    f32x2 s2v = q[0] + q[1] + q[2] + q[3];
    f32x2 ss2 = q[0] * q[0] + q[1] * q[1] + q[2] * q[2] + q[3] * q[3];
    float s  = s2v[0] + s2v[1];
    float ss = ss2[0] + ss2[1];
    float v8[8];
#pragma unroll
    for (int hh = 0; hh < 8; ++hh) {
      const float4 w0 = *(const float4*)&gw_s[hh][j0];
      const float4 w1 = *(const float4*)&gw_s[hh][j1];
      f32x2 g0, g1, g2, g3;
      split4(w0, g0, g1); split4(w1, g2, g3);
      f32x2 d = q[0] * g0 + q[1] * g1 + q[2] * g2 + q[3] * g3;
      v8[hh] = d[0] + d[1];
    }
    s = wsum(s); ss = wsum(ss);
    const float mean = s * (1.f / 512.f);
    const float rstd = rsqrtf(ss * (1.f / 512.f) - mean * mean + 1e-5f);
    {
      const float4 gg0 = *(const float4*)&g_s[j0];
      const float4 bb0 = *(const float4*)&b_s[j0];
      const float4 gg1 = *(const float4*)&g_s[j1];
      const float4 bb1 = *(const float4*)&b_s[j1];
      s16x4 o0, o1;
      o0[0] = f2bf((x0.x - mean) * rstd * gg0.x + bb0.x);
      o0[1] = f2bf((x0.y - mean) * rstd * gg0.y + bb0.y);
      o0[2] = f2bf((x0.z - mean) * rstd * gg0.z + bb0.z);
      o0[3] = f2bf((x0.w - mean) * rstd * gg0.w + bb0.w);
      o1[0] = f2bf((x1.x - mean) * rstd * gg1.x + bb1.x);
      o1[1] = f2bf((x1.y - mean) * rstd * gg1.y + bb1.y);
      o1[2] = f2bf((x1.z - mean) * rstd * gg1.z + bb1.z);
      o1[3] = f2bf((x1.w - mean) * rstd * gg1.w + bb1.w);
      *(s16x4*)&h2_s[k][j0] = o0;
      *(s16x4*)&h2_s[k][j1] = o1;
    }
    const float z = fold8(v8, lane);
    const float zf = rstd * 0.125f * (z - mean * sg_r) + bw8_r;
    if (lane < 8) sc2_s[lane][k] = zf;
  }
  __syncthreads();

  // ---- cross-wave A combine into gw_s region (float4)
  for (int wv = 0; wv < 4; ++wv) {
    if (w == wv) {
#pragma unroll
      for (int hh = 0; hh < 8; ++hh) {
        float4* p0 = (float4*)&gw_s[hh][j0];
        float4* p1 = (float4*)&gw_s[hh][j1];
        const float4 a0 = make_float4(A2[hh][0][0], A2[hh][0][1],
                                      A2[hh][1][0], A2[hh][1][1]);
        const float4 a1 = make_float4(A2[hh][2][0], A2[hh][2][1],
                                      A2[hh][3][0], A2[hh][3][1]);
        if (wv == 0) { *p0 = a0; *p1 = a1; }
        else {
          float4 v0 = *p0, v1 = *p1;
          v0.x += a0.x; v0.y += a0.y; v0.z += a0.z; v0.w += a0.w;
          v1.x += a1.x; v1.y += a1.y; v1.z += a1.z; v1.w += a1.w;
          *p0 = v0; *p1 = v1;
        }
      }
    }
    __syncthreads();
  }

  if (tid < 8) {
    float Bt = 0.f, Lt = 0.f;
    for (int wv = 0; wv < 4; ++wv) { Bt += wstatB[wv][tid]; Lt += wstatL[wv][tid]; }
    float den = Lt;
#pragma unroll
    for (int k = 0; k < 5; ++k) {
      const float e = __expf(sc2_s[tid][k]);
      e2_s[tid][k] = e; den += e;
    }
    Bt_s[tid] = Bt; Lt_s[tid] = Lt; inv_s[tid] = 1.f / den;
  }
  __syncthreads();

  // ---- u[hh][j] (bf16) = ((g*(A-B) + b*L + sum_k e2*h2) / den)
  __hip_bfloat16* dst = u_out + (size_t)n * 4096;
  for (int bidx = tid * 4; bidx < 4096; bidx += 1024) {
    const int hh = bidx >> 9, j = bidx & 511;
    const float4 a4 = *(const float4*)&gw_s[hh][j];
    const float4 g4 = *(const float4*)&g_s[j];
    const float4 b4 = *(const float4*)&b_s[j];
    const float Bt = Bt_s[hh], Lt = Lt_s[hh];
    float v0 = (a4.x - Bt) * g4.x + Lt * b4.x;
    float v1 = (a4.y - Bt) * g4.y + Lt * b4.y;
    float v2 = (a4.z - Bt) * g4.z + Lt * b4.z;
    float v3 = (a4.w - Bt) * g4.w + Lt * b4.w;
#pragma unroll
    for (int k = 0; k < 5; ++k) {
      const s16x4 hq = *(const s16x4*)&h2_s[k][j];
      const float e = e2_s[hh][k];
      v0 += e * bfs2f(hq[0]); v1 += e * bfs2f(hq[1]);
      v2 += e * bfs2f(hq[2]); v3 += e * bfs2f(hq[3]);
    }
    const float iv = inv_s[hh];
    s16x4 o;
    o[0] = f2bf(v0 * iv); o[1] = f2bf(v1 * iv);
    o[2] = f2bf(v2 * iv); o[3] = f2bf(v3 * iv);
    *(s16x4*)&dst[bidx] = o;
  }
}

// ---------------------------------------------------------------------------
extern "C" void kernel_launch(void* const* d_in, const int* in_sizes, int n_in,
                              void* d_out, int out_size, void* d_ws, size_t ws_size,
                              hipStream_t stream)
{
  const float* images = (const float*)d_in[0];
  const float* W_img  = (const float*)d_in[1];
  const float* ctx    = (const float*)d_in[2];
  const float* cls    = (const float*)d_in[3];
  const float* ln_g   = (const float*)d_in[4];
  const float* ln_b   = (const float*)d_in[5];
  const float* Wq     = (const float*)d_in[6];
  const float* Wk     = (const float*)d_in[7];
  const float* Wv     = (const float*)d_in[8];
  const float* Wo     = (const float*)d_in[9];
  const float* tproj  = (const float*)d_in[10];
  const float* lscale = (const float*)d_in[11];

  __hip_bfloat16* wtu = (__hip_bfloat16*)d_ws;  // wt -> u (bf16, in place)
  float* fws  = (float*)d_ws;
  float* img  = fws + 2048000;
  float* hlO  = img + 131072;       // O
  float* qo2  = hlO + 512000;       // q -> out2
  float* txt  = fws;                // alias over dead u region
  (void)in_sizes; (void)n_in; (void)out_size; (void)ws_size;

  // 1) image embedding (bf16 MFMA), unnormalized (logits_k normalizes)
  gemm_mfma_k<0,0,0,0><<<dim3(8,4,1),256,0,stream>>>(images,768,0, W_img,512,0,
      img,512,0, nullptr,0, 256,512,768);

  // 2) q = LN(cls_last) @ Wq  (LN fused into staging)
  gemm_mfma_lnA_k<<<dim3(8,16),256,0,stream>>>(cls + 71*512, 72*512,
      ln_g, ln_b, Wq,512, qo2,512, 1000,512,512);

  // 3) wt = per-head q @ Wk^T  -> bf16
  gemm_mfma_k<1,0,0,1><<<dim3(8,16,8),256,0,stream>>>(qo2,512,64, Wk,512,64,
      wtu,4096,512, nullptr,0, 1000,512,64);

  // 4+5) fused pass1+pass2 sweep -> u bf16 (in place over wt)
  fused_sweep_kernel<<<1000,256,0,stream>>>(ctx, cls, ln_g, ln_b, wtu, wtu);

  // 6) O = per-head u @ Wv  (A read directly as bf16)
  gemm_mfma_k<0,0,1,0><<<dim3(1,16,8),256,0,stream>>>(wtu,4096,512, Wv,512,64,
      hlO,512,64, nullptr,0, 1000,64,512);

  // 7) out2 = cls_last + O @ Wo ; txt = out2 @ text_proj  (bf16 MFMA)
  gemm_mfma_k<0,1,0,0><<<dim3(8,16,1),256,0,stream>>>(hlO,512,0, Wo,512,0,
      qo2,512,0, cls + 71*512, 72*512, 1000,512,512);
  gemm_mfma_k<0,0,0,0><<<dim3(8,16,1),256,0,stream>>>(qo2,512,0, tproj,512,0,
      txt,512,0, nullptr,0, 1000,512,512);

  // 8) logits = exp(ls) * (img/|img|) @ (txt/|txt|)^T  (norms fused, f32)
  logits_k<<<dim3(16,8),256,0,stream>>>(img,512, txt,512,
      (float*)d_out,1000, lscale, 256,1000,512);
}

// Round 16
// 149.722 us; speedup vs baseline: 1.1705x; 1.0270x over previous
//
#include <hip/hip_runtime.h>
#include <hip/hip_bf16.h>

#define DEV static __device__ __forceinline__

typedef __attribute__((ext_vector_type(8))) short bf16x8;
typedef __attribute__((ext_vector_type(4))) short s16x4;
typedef __attribute__((ext_vector_type(4))) float f32x4;
typedef __attribute__((ext_vector_type(2))) float f32x2;

DEV float wsum(float v) {
  v += __shfl_xor(v, 1);  v += __shfl_xor(v, 2);  v += __shfl_xor(v, 4);
  v += __shfl_xor(v, 8);  v += __shfl_xor(v, 16); v += __shfl_xor(v, 32);
  return v;
}
DEV float wmaxr(float v) {
  v = fmaxf(v, __shfl_xor(v, 1));  v = fmaxf(v, __shfl_xor(v, 2));
  v = fmaxf(v, __shfl_xor(v, 4));  v = fmaxf(v, __shfl_xor(v, 8));
  v = fmaxf(v, __shfl_xor(v, 16)); v = fmaxf(v, __shfl_xor(v, 32));
  return v;
}
DEV short f2bf(float x) {
  __hip_bfloat16 h = __float2bfloat16(x);
  return *reinterpret_cast<short*>(&h);
}
DEV float bf2f(unsigned int u) {
  const unsigned int x = u << 16;
  return __uint_as_float(x);
}
DEV float bfs2f(short s) {
  const unsigned int x = ((unsigned int)(unsigned short)s) << 16;
  return __uint_as_float(x);
}
DEV void split4(const float4& v, f32x2& lo, f32x2& hi) {
  lo = f32x2{v.x, v.y}; hi = f32x2{v.z, v.w};
}

// Fold-reduce 8 per-lane values across 64 lanes -> full sum of head (lane&7).
DEV float fold8(const float v[8], int lane) {
  float w4[4];
#pragma unroll
  for (int j = 0; j < 4; ++j) {
    const float mine  = (lane & 1) ? v[2 * j + 1] : v[2 * j];
    const float other = (lane & 1) ? v[2 * j]     : v[2 * j + 1];
    w4[j] = mine + __shfl_xor(other, 1);
  }
  float u2[2];
#pragma unroll
  for (int j = 0; j < 2; ++j) {
    const float mine  = (lane & 2) ? w4[2 * j + 1] : w4[2 * j];
    const float other = (lane & 2) ? w4[2 * j]     : w4[2 * j + 1];
    u2[j] = mine + __shfl_xor(other, 2);
  }
  const float mine  = (lane & 4) ? u2[1] : u2[0];
  const float other = (lane & 4) ? u2[0] : u2[1];
  float z = mine + __shfl_xor(other, 4);
  z += __shfl_xor(z, 8); z += __shfl_xor(z, 16); z += __shfl_xor(z, 32);
  return z;
}

// ---------------------------------------------------------------------------
// Unified bf16 MFMA GEMM: 64x64 tile, depth-2 register prefetch + LDS dbuf.
// (HW-validated rounds 12-15; used for img + wt GEMMs)
// ---------------------------------------------------------------------------
template <int TRANSB, int ADDD, int ABF16, int OUTBF16>
__global__ __launch_bounds__(256) void gemm_mfma_k(
    const void* __restrict__ Av, int lda, long long bsA,
    const float* __restrict__ B, int ldb, long long bsB,
    void* __restrict__ Cv, int ldc, long long bsC,
    const float* __restrict__ D, long long ldd,
    int M, int N, int K)
{
  const float* Af = (const float*)Av + (ABF16 ? 0 : (size_t)blockIdx.z * bsA);
  const short* Ah = (const short*)Av + (ABF16 ? (size_t)blockIdx.z * bsA : 0);
  B += (size_t)blockIdx.z * bsB;
  const int m0 = blockIdx.y * 64, n0 = blockIdx.x * 64;
  const int tid = threadIdx.x;
  const int w = tid >> 6, lane = tid & 63;
  const int wr = w >> 1, wc = w & 1;
  __shared__ __attribute__((aligned(16))) short As[2][64][40];
  __shared__ __attribute__((aligned(16))) short Bs[2][64][40];
  f32x4 acc[2][2] = {};

  const int ar = tid >> 2, akc = (tid & 3) * 8;
  const int br = tid >> 3, bnc = (tid & 7) * 8;
  const bool arv = (m0 + ar < M);
  const int rbase = wr * 32 + (lane & 15);
  const int cbase = wc * 32 + (lane & 15);
  const int kb = (lane >> 4) * 8;

  auto gload = [&](int k0, float4& a0, float4& a1, bf16x8& ah,
                   float4& b0, float4& b1) {
    if (ABF16) {
      ah = bf16x8{};
      if (arv) ah = *(const bf16x8*)(Ah + (size_t)(m0 + ar) * lda + k0 + akc);
    } else {
      a0 = make_float4(0.f, 0.f, 0.f, 0.f); a1 = a0;
      if (arv) {
        a0 = *(const float4*)(Af + (size_t)(m0 + ar) * lda + k0 + akc);
        a1 = *(const float4*)(Af + (size_t)(m0 + ar) * lda + k0 + akc + 4);
      }
    }
    if (TRANSB) {
      b0 = *(const float4*)(B + (size_t)(n0 + ar) * ldb + k0 + akc);
      b1 = *(const float4*)(B + (size_t)(n0 + ar) * ldb + k0 + akc + 4);
    } else {
      b0 = *(const float4*)(B + (size_t)(k0 + br) * ldb + n0 + bnc);
      b1 = *(const float4*)(B + (size_t)(k0 + br) * ldb + n0 + bnc + 4);
    }
  };
  auto stage = [&](int buf, const float4& a0, const float4& a1, const bf16x8& ah,
                   const float4& b0, const float4& b1) {
    if (ABF16) {
      *(bf16x8*)&As[buf][ar][akc] = ah;
    } else {
      bf16x8 av;
      av[0] = f2bf(a0.x); av[1] = f2bf(a0.y); av[2] = f2bf(a0.z); av[3] = f2bf(a0.w);
      av[4] = f2bf(a1.x); av[5] = f2bf(a1.y); av[6] = f2bf(a1.z); av[7] = f2bf(a1.w);
      *(bf16x8*)&As[buf][ar][akc] = av;
    }
    if (TRANSB) {
      bf16x8 bv;
      bv[0] = f2bf(b0.x); bv[1] = f2bf(b0.y); bv[2] = f2bf(b0.z); bv[3] = f2bf(b0.w);
      bv[4] = f2bf(b1.x); bv[5] = f2bf(b1.y); bv[6] = f2bf(b1.z); bv[7] = f2bf(b1.w);
      *(bf16x8*)&Bs[buf][ar][akc] = bv;
    } else {
      Bs[buf][bnc + 0][br] = f2bf(b0.x); Bs[buf][bnc + 1][br] = f2bf(b0.y);
      Bs[buf][bnc + 2][br] = f2bf(b0.z); Bs[buf][bnc + 3][br] = f2bf(b0.w);
      Bs[buf][bnc + 4][br] = f2bf(b1.x); Bs[buf][bnc + 5][br] = f2bf(b1.y);
      Bs[buf][bnc + 6][br] = f2bf(b1.z); Bs[buf][bnc + 7][br] = f2bf(b1.w);
    }
  };
  auto compute = [&](int buf) {
    bf16x8 af0 = *(const bf16x8*)&As[buf][rbase][kb];
    bf16x8 af1 = *(const bf16x8*)&As[buf][rbase + 16][kb];
    bf16x8 bf0 = *(const bf16x8*)&Bs[buf][cbase][kb];
    bf16x8 bf1 = *(const bf16x8*)&Bs[buf][cbase + 16][kb];
    acc[0][0] = __builtin_amdgcn_mfma_f32_16x16x32_bf16(af0, bf0, acc[0][0], 0, 0, 0);
    acc[0][1] = __builtin_amdgcn_mfma_f32_16x16x32_bf16(af0, bf1, acc[0][1], 0, 0, 0);
    acc[1][0] = __builtin_amdgcn_mfma_f32_16x16x32_bf16(af1, bf0, acc[1][0], 0, 0, 0);
    acc[1][1] = __builtin_amdgcn_mfma_f32_16x16x32_bf16(af1, bf1, acc[1][1], 0, 0, 0);
  };

  float4 a0A, a1A, b0A, b1A, a0B, a1B, b0B, b1B;
  bf16x8 ahA = {}, ahB = {};
  gload(0, a0A, a1A, ahA, b0A, b1A);
  gload(32, a0B, a1B, ahB, b0B, b1B);
  for (int k0 = 0; k0 < K; k0 += 64) {
    stage(0, a0A, a1A, ahA, b0A, b1A);
    if (k0 + 64 < K) gload(k0 + 64, a0A, a1A, ahA, b0A, b1A);
    __syncthreads();
    compute(0);
    stage(1, a0B, a1B, ahB, b0B, b1B);
    if (k0 + 96 < K) gload(k0 + 96, a0B, a1B, ahB, b0B, b1B);
    __syncthreads();
    compute(1);
  }

  const size_t cb = (size_t)blockIdx.z * (size_t)bsC;
#pragma unroll
  for (int mi = 0; mi < 2; ++mi)
#pragma unroll
    for (int ni = 0; ni < 2; ++ni)
#pragma unroll
      for (int r = 0; r < 4; ++r) {
        const int row = m0 + wr * 32 + mi * 16 + (lane >> 4) * 4 + r;
        const int col = n0 + wc * 32 + ni * 16 + (lane & 15);
        if (row < M) {
          float v = acc[mi][ni][r];
          if (ADDD) v += D[(size_t)row * ldd + col];
          if (OUTBF16)
            ((__hip_bfloat16*)Cv)[cb + (size_t)row * ldc + col] = __float2bfloat16(v);
          else
            ((float*)Cv)[cb + (size_t)row * ldc + col] = v;
        }
      }
}

// ---------------------------------------------------------------------------
// NEW: 32x64-tile bf16 MFMA GEMM — doubles grid for M=1000 GEMMs (Wo, tproj,
// O) to 256 blocks = full chip. 2x2 waves, 1 A-frag + 2 B-frags, 2 MFMA per
// K-step, LDS 15.4 KB dbuf, same depth-2 prefetch schedule. B-staging map is
// identical to the 64-tile (B tile is 32k x 64n in both). f32 output.
// ---------------------------------------------------------------------------
template <int ADDD, int ABF16>
__global__ __launch_bounds__(256) void gemm32_mfma_k(
    const void* __restrict__ Av, int lda, long long bsA,
    const float* __restrict__ B, int ldb, long long bsB,
    float* __restrict__ C, int ldc, long long bsC,
    const float* __restrict__ D, long long ldd,
    int M, int N, int K)
{
  const float* Af = (const float*)Av + (ABF16 ? 0 : (size_t)blockIdx.z * bsA);
  const short* Ah = (const short*)Av + (ABF16 ? (size_t)blockIdx.z * bsA : 0);
  B += (size_t)blockIdx.z * bsB;
  const int m0 = blockIdx.y * 32, n0 = blockIdx.x * 64;
  const int tid = threadIdx.x;
  const int w = tid >> 6, lane = tid & 63;
  const int wr = w >> 1, wc = w & 1;
  __shared__ __attribute__((aligned(16))) short As[2][32][40];
  __shared__ __attribute__((aligned(16))) short Bs[2][64][40];
  f32x4 acc[2] = {};

  const int ar = tid >> 3, akc = (tid & 7) * 4;   // A: 32 rows x 32 k, 4/thr
  const int br = tid >> 3, bnc = (tid & 7) * 8;   // B: 32 k x 64 n (as 64-tile)
  const bool arv = (m0 + ar < M);
  const int rbase = wr * 16 + (lane & 15);
  const int cbase = wc * 32 + (lane & 15);
  const int kb = (lane >> 4) * 8;

  auto gload = [&](int k0, float4& a0, s16x4& ah, float4& b0, float4& b1) {
    if (ABF16) {
      ah = s16x4{};
      if (arv) ah = *(const s16x4*)(Ah + (size_t)(m0 + ar) * lda + k0 + akc);
    } else {
      a0 = make_float4(0.f, 0.f, 0.f, 0.f);
      if (arv) a0 = *(const float4*)(Af + (size_t)(m0 + ar) * lda + k0 + akc);
    }
    b0 = *(const float4*)(B + (size_t)(k0 + br) * ldb + n0 + bnc);
    b1 = *(const float4*)(B + (size_t)(k0 + br) * ldb + n0 + bnc + 4);
  };
  auto stage = [&](int buf, const float4& a0, const s16x4& ah,
                   const float4& b0, const float4& b1) {
    if (ABF16) {
      *(s16x4*)&As[buf][ar][akc] = ah;
    } else {
      s16x4 av;
      av[0] = f2bf(a0.x); av[1] = f2bf(a0.y);
      av[2] = f2bf(a0.z); av[3] = f2bf(a0.w);
      *(s16x4*)&As[buf][ar][akc] = av;
    }
    Bs[buf][bnc + 0][br] = f2bf(b0.x); Bs[buf][bnc + 1][br] = f2bf(b0.y);
    Bs[buf][bnc + 2][br] = f2bf(b0.z); Bs[buf][bnc + 3][br] = f2bf(b0.w);
    Bs[buf][bnc + 4][br] = f2bf(b1.x); Bs[buf][bnc + 5][br] = f2bf(b1.y);
    Bs[buf][bnc + 6][br] = f2bf(b1.z); Bs[buf][bnc + 7][br] = f2bf(b1.w);
  };
  auto compute = [&](int buf) {
    bf16x8 af  = *(const bf16x8*)&As[buf][rbase][kb];
    bf16x8 bf0 = *(const bf16x8*)&Bs[buf][cbase][kb];
    bf16x8 bf1 = *(const bf16x8*)&Bs[buf][cbase + 16][kb];
    acc[0] = __builtin_amdgcn_mfma_f32_16x16x32_bf16(af, bf0, acc[0], 0, 0, 0);
    acc[1] = __builtin_amdgcn_mfma_f32_16x16x32_bf16(af, bf1, acc[1], 0, 0, 0);
  };

  float4 a0A, b0A, b1A, a0B, b0B, b1B;
  s16x4 ahA = {}, ahB = {};
  gload(0, a0A, ahA, b0A, b1A);
  gload(32, a0B, ahB, b0B, b1B);
  for (int k0 = 0; k0 < K; k0 += 64) {
    stage(0, a0A, ahA, b0A, b1A);
    if (k0 + 64 < K) gload(k0 + 64, a0A, ahA, b0A, b1A);
    __syncthreads();
    compute(0);
    stage(1, a0B, ahB, b0B, b1B);
    if (k0 + 96 < K) gload(k0 + 96, a0B, ahB, b0B, b1B);
    __syncthreads();
    compute(1);
  }

  const size_t cb = (size_t)blockIdx.z * (size_t)bsC;
#pragma unroll
  for (int ni = 0; ni < 2; ++ni)
#pragma unroll
    for (int r = 0; r < 4; ++r) {
      const int row = m0 + wr * 16 + (lane >> 4) * 4 + r;
      const int col = n0 + wc * 32 + ni * 16 + (lane & 15);
      if (row < M) {
        float v = acc[ni][r];
        if (ADDD) v += D[(size_t)row * ldd + col];
        C[cb + (size_t)row * ldc + col] = v;
      }
    }
}

// ---------------------------------------------------------------------------
// bf16 MFMA GEMM with LayerNorm fused on A (unchanged).
// ---------------------------------------------------------------------------
__global__ __launch_bounds__(256) void gemm_mfma_lnA_k(
    const float* __restrict__ A, long long lda,
    const float* __restrict__ g, const float* __restrict__ b,
    const float* __restrict__ B, int ldb,
    float* __restrict__ C, int ldc,
    int M, int N, int K)
{
  const int m0 = blockIdx.y * 64, n0 = blockIdx.x * 64;
  const int tid = threadIdx.x;
  const int w = tid >> 6, lane = tid & 63;
  const int wr = w >> 1, wc = w & 1;
  __shared__ __attribute__((aligned(16))) short As[2][64][40];
  __shared__ __attribute__((aligned(16))) short Bs[2][64][40];
  __shared__ __attribute__((aligned(16))) float g_s[512], b_s[512];
  __shared__ float mean_s[64], rstd_s[64];
  f32x4 acc[2][2] = {};

  if (tid < 128) ((float4*)g_s)[tid] = ((const float4*)g)[tid];
  else ((float4*)b_s)[tid - 128] = ((const float4*)b)[tid - 128];

  {
    const int r = tid >> 2, p = tid & 3;
    float s = 0.f, ss = 0.f;
    if (m0 + r < M) {
      const float4* src = (const float4*)(A + (size_t)(m0 + r) * lda + p * 128);
#pragma unroll 8
      for (int i = 0; i < 32; ++i) {
        const float4 v = src[i];
        s += v.x + v.y + v.z + v.w;
        ss += v.x * v.x + v.y * v.y + v.z * v.z + v.w * v.w;
      }
    }
    s += __shfl_xor(s, 1);  s += __shfl_xor(s, 2);
    ss += __shfl_xor(ss, 1); ss += __shfl_xor(ss, 2);
    if (p == 0) {
      const float mean = s * (1.f / 512.f);
      mean_s[r] = mean;
      rstd_s[r] = rsqrtf(ss * (1.f / 512.f) - mean * mean + 1e-5f);
    }
  }
  __syncthreads();

  const int ar = tid >> 2, akc = (tid & 3) * 8;
  const int br = tid >> 3, bnc = (tid & 7) * 8;
  const bool arv = (m0 + ar < M);
  const int rbase = wr * 32 + (lane & 15);
  const int cbase = wc * 32 + (lane & 15);
  const int kb = (lane >> 4) * 8;

  auto gload = [&](int k0, float4& a0, float4& a1, float4& b0, float4& b1) {
    a0 = make_float4(0.f, 0.f, 0.f, 0.f); a1 = a0;
    if (arv) {
      a0 = *(const float4*)(A + (size_t)(m0 + ar) * lda + k0 + akc);
      a1 = *(const float4*)(A + (size_t)(m0 + ar) * lda + k0 + akc + 4);
    }
    b0 = *(const float4*)(B + (size_t)(k0 + br) * ldb + n0 + bnc);
    b1 = *(const float4*)(B + (size_t)(k0 + br) * ldb + n0 + bnc + 4);
  };
  auto stage = [&](int buf, int k0, const float4& a0, const float4& a1,
                   const float4& b0, const float4& b1) {
    const float mn = mean_s[ar], rs = rstd_s[ar];
    const int kc = k0 + akc;
    bf16x8 av;
    av[0] = f2bf((a0.x - mn) * rs * g_s[kc + 0] + b_s[kc + 0]);
    av[1] = f2bf((a0.y - mn) * rs * g_s[kc + 1] + b_s[kc + 1]);
    av[2] = f2bf((a0.z - mn) * rs * g_s[kc + 2] + b_s[kc + 2]);
    av[3] = f2bf((a0.w - mn) * rs * g_s[kc + 3] + b_s[kc + 3]);
    av[4] = f2bf((a1.x - mn) * rs * g_s[kc + 4] + b_s[kc + 4]);
    av[5] = f2bf((a1.y - mn) * rs * g_s[kc + 5] + b_s[kc + 5]);
    av[6] = f2bf((a1.z - mn) * rs * g_s[kc + 6] + b_s[kc + 6]);
    av[7] = f2bf((a1.w - mn) * rs * g_s[kc + 7] + b_s[kc + 7]);
    *(bf16x8*)&As[buf][ar][akc] = av;
    Bs[buf][bnc + 0][br] = f2bf(b0.x); Bs[buf][bnc + 1][br] = f2bf(b0.y);
    Bs[buf][bnc + 2][br] = f2bf(b0.z); Bs[buf][bnc + 3][br] = f2bf(b0.w);
    Bs[buf][bnc + 4][br] = f2bf(b1.x); Bs[buf][bnc + 5][br] = f2bf(b1.y);
    Bs[buf][bnc + 6][br] = f2bf(b1.z); Bs[buf][bnc + 7][br] = f2bf(b1.w);
  };
  auto compute = [&](int buf) {
    bf16x8 af0 = *(const bf16x8*)&As[buf][rbase][kb];
    bf16x8 af1 = *(const bf16x8*)&As[buf][rbase + 16][kb];
    bf16x8 bf0 = *(const bf16x8*)&Bs[buf][cbase][kb];
    bf16x8 bf1 = *(const bf16x8*)&Bs[buf][cbase + 16][kb];
    acc[0][0] = __builtin_amdgcn_mfma_f32_16x16x32_bf16(af0, bf0, acc[0][0], 0, 0, 0);
    acc[0][1] = __builtin_amdgcn_mfma_f32_16x16x32_bf16(af0, bf1, acc[0][1], 0, 0, 0);
    acc[1][0] = __builtin_amdgcn_mfma_f32_16x16x32_bf16(af1, bf0, acc[1][0], 0, 0, 0);
    acc[1][1] = __builtin_amdgcn_mfma_f32_16x16x32_bf16(af1, bf1, acc[1][1], 0, 0, 0);
  };

  float4 a0A, a1A, b0A, b1A, a0B, a1B, b0B, b1B;
  gload(0, a0A, a1A, b0A, b1A);
  gload(32, a0B, a1B, b0B, b1B);
  for (int k0 = 0; k0 < K; k0 += 64) {
    stage(0, k0, a0A, a1A, b0A, b1A);
    if (k0 + 64 < K) gload(k0 + 64, a0A, a1A, b0A, b1A);
    __syncthreads();
    compute(0);
    stage(1, k0 + 32, a0B, a1B, b0B, b1B);
    if (k0 + 96 < K) gload(k0 + 96, a0B, a1B, b0B, b1B);
    __syncthreads();
    compute(1);
  }

#pragma unroll
  for (int mi = 0; mi < 2; ++mi)
#pragma unroll
    for (int ni = 0; ni < 2; ++ni)
#pragma unroll
      for (int r = 0; r < 4; ++r) {
        const int row = m0 + wr * 32 + mi * 16 + (lane >> 4) * 4 + r;
        const int col = n0 + wc * 32 + ni * 16 + (lane & 15);
        if (row < M) C[(size_t)row * ldc + col] = acc[mi][ni][r];
      }
}

// ---------------------------------------------------------------------------
// Logits GEMM with fused L2 norms (unchanged).
// ---------------------------------------------------------------------------
__global__ __launch_bounds__(256) void logits_k(
    const float* __restrict__ A, int lda,
    const float* __restrict__ B, int ldb,
    float* __restrict__ C, int ldc,
    const float* __restrict__ alpha_ptr,
    int M, int N, int K)
{
  const int m0 = blockIdx.y * 32, n0 = blockIdx.x * 64;
  const int tid = threadIdx.x;
  __shared__ __attribute__((aligned(16))) float As[2][16][36];
  __shared__ __attribute__((aligned(16))) float Bs[2][16][68];
  __shared__ float nA[32], nB[64];
  float acc[2][4] = {};
  float ssA = 0.f, ssB = 0.f;
  const int ty = tid >> 4, tx = tid & 15;
  const int am = tid >> 3, ak = (tid & 7) * 2;
  const int bm = tid >> 2, bt = (tid & 3) * 4;
  const bool aval = (m0 + am < M);
  const bool bval = (n0 + bm < N);

  float2 av; float4 bv;
  auto gload = [&](int k0) {
    av = make_float2(0.f, 0.f);
    bv = make_float4(0.f, 0.f, 0.f, 0.f);
    if (aval) av = *(const float2*)(A + (size_t)(m0 + am) * lda + (k0 + ak));
    if (bval) bv = *(const float4*)(B + (size_t)(n0 + bm) * ldb + (k0 + bt));
    ssA += av.x * av.x + av.y * av.y;
    ssB += bv.x * bv.x + bv.y * bv.y + bv.z * bv.z + bv.w * bv.w;
  };
  auto sstore = [&](int buf) {
    As[buf][ak][am] = av.x; As[buf][ak + 1][am] = av.y;
    Bs[buf][bt + 0][bm] = bv.x; Bs[buf][bt + 1][bm] = bv.y;
    Bs[buf][bt + 2][bm] = bv.z; Bs[buf][bt + 3][bm] = bv.w;
  };

  const int nIt = K >> 4;
  gload(0); sstore(0);
  for (int it = 0; it < nIt; ++it) {
    __syncthreads();
    if (it + 1 < nIt) gload((it + 1) << 4);
    const int buf = it & 1;
#pragma unroll
    for (int kk = 0; kk < 16; ++kk) {
      const float2 a  = *(const float2*)&As[buf][kk][ty * 2];
      const float4 bq = *(const float4*)&Bs[buf][kk][tx * 4];
      acc[0][0] += a.x * bq.x; acc[0][1] += a.x * bq.y; acc[0][2] += a.x * bq.z; acc[0][3] += a.x * bq.w;
      acc[1][0] += a.y * bq.x; acc[1][1] += a.y * bq.y; acc[1][2] += a.y * bq.z; acc[1][3] += a.y * bq.w;
    }
    if (it + 1 < nIt) sstore((it + 1) & 1);
  }

  ssA += __shfl_xor(ssA, 1); ssA += __shfl_xor(ssA, 2); ssA += __shfl_xor(ssA, 4);
  if ((tid & 7) == 0) nA[am] = rsqrtf(ssA);
  ssB += __shfl_xor(ssB, 1); ssB += __shfl_xor(ssB, 2);
  if ((tid & 3) == 0) nB[bm] = rsqrtf(ssB);
  __syncthreads();

  const float alpha = __expf(alpha_ptr[0]);
#pragma unroll
  for (int i = 0; i < 2; ++i) {
    const int m = m0 + ty * 2 + i;
    if (m >= M) continue;
    const float fa = alpha * nA[ty * 2 + i];
#pragma unroll
    for (int j = 0; j < 4; ++j) {
      const int nn = n0 + tx * 4 + j;
      if (nn < N) C[(size_t)m * ldc + nn] = acc[i][j] * fa * nB[tx * 4 + j];
    }
  }
}

// ---------------------------------------------------------------------------
// FUSED sweep v8 (round-13/15 state — best known-good, 90 us, frozen).
// ---------------------------------------------------------------------------
__global__ __launch_bounds__(256) void fused_sweep_kernel(
    const float* __restrict__ ctx, const float* __restrict__ cls,
    const float* __restrict__ g, const float* __restrict__ b,
    const __hip_bfloat16* __restrict__ wt, __hip_bfloat16* __restrict__ u_out)
{
  const int n = blockIdx.x, tid = threadIdx.x;
  const int w = tid >> 6, lane = tid & 63;
  __shared__ __attribute__((aligned(16))) float gw_s[8][512];
  __shared__ __attribute__((aligned(16))) float g_s[512], b_s[512];
  __shared__ __attribute__((aligned(16))) short h2_s[5][512];
  __shared__ float sc_s[8][80];
  __shared__ float sc2_s[8][5];
  __shared__ float ah_s[8][5];
  __shared__ float wstatB[4][8], wstatL[4][8];
  __shared__ float attr_s[5];
  __shared__ float Sgw_l[8], bw_l[8];
  __shared__ float Bt_s[8], Lt_s[8], inv_s[8];
  __shared__ float e2_s[8][5];
  __shared__ __attribute__((aligned(16))) float es_s[4][2][8];

  {
    const uint4* wsrc = (const uint4*)(wt + (size_t)n * 4096);
    float4* gwf = (float4*)&gw_s[0][0];
    for (int i = tid; i < 512; i += 256) {
      const uint4 v = wsrc[i];
      gwf[i * 2]     = make_float4(bf2f(v.x & 0xffffu), bf2f(v.x >> 16),
                                   bf2f(v.y & 0xffffu), bf2f(v.y >> 16));
      gwf[i * 2 + 1] = make_float4(bf2f(v.z & 0xffffu), bf2f(v.z >> 16),
                                   bf2f(v.w & 0xffffu), bf2f(v.w >> 16));
    }
    if (tid < 128) ((float4*)g_s)[tid] = ((const float4*)g)[tid];
    else ((float4*)b_s)[tid - 128] = ((const float4*)b)[tid - 128];
  }
  __syncthreads();

  for (int hh = w; hh < 8; hh += 4) {
    float s1 = 0.f, s2 = 0.f;
#pragma unroll
    for (int i = 0; i < 8; ++i) {
      const int j = lane + 64 * i;
      const float wv = gw_s[hh][j];
      const float gv = wv * g_s[j];
      s1 += gv; s2 += wv * b_s[j];
      gw_s[hh][j] = gv;
    }
    s1 = wsum(s1); s2 = wsum(s2);
    if (lane == 0) { Sgw_l[hh] = s1; bw_l[hh] = s2; }
  }
  __syncthreads();
  const float sg_r  = Sgw_l[lane & 7];
  const float bw8_r = bw_l[lane & 7] * 0.125f;
  const int j0 = lane * 4, j1 = lane * 4 + 256;

  // ---- stage A: 5 unscaled ctx rows (global reads) -> pass-1 scores
  for (int k = w; k < 5; k += 4) {
    const float* src = ctx + ((size_t)n * 5 + k) * 512;
    const float4 x0 = *(const float4*)(src + j0);
    const float4 x1 = *(const float4*)(src + j1);
    f32x2 q[4];
    split4(x0, q[0], q[1]); split4(x1, q[2], q[3]);
    f32x2 s2v = q[0] + q[1] + q[2] + q[3];
    f32x2 ss2 = q[0] * q[0] + q[1] * q[1] + q[2] * q[2] + q[3] * q[3];
    float s  = s2v[0] + s2v[1];
    float ss = ss2[0] + ss2[1];
    float v8[8];
#pragma unroll
    for (int hh = 0; hh < 8; ++hh) {
      const float4 w0 = *(const float4*)&gw_s[hh][j0];
      const float4 w1 = *(const float4*)&gw_s[hh][j1];
      f32x2 g0, g1, g2, g3;
      split4(w0, g0, g1); split4(w1, g2, g3);
      f32x2 d = q[0] * g0 + q[1] * g1 + q[2] * g2 + q[3] * g3;
      v8[hh] = d[0] + d[1];
    }
    s = wsum(s); ss = wsum(ss);
    const float mean = s * (1.f / 512.f);
    const float rstd = rsqrtf(ss * (1.f / 512.f) - mean * mean + 1e-5f);
    const float z = fold8(v8, lane);
    const float zf = rstd * 0.125f * (z - mean * sg_r) + bw8_r;
    if (lane < 8) sc_s[lane][k] = zf;
  }

  // ---- stage B: 72 cls rows, 9 pairs/wave, prefetch depth 2, f32x2 math
  f32x2 A2[8][4];
#pragma unroll
  for (int hh = 0; hh < 8; ++hh)
#pragma unroll
    for (int i = 0; i < 4; ++i) A2[hh][i] = f32x2{0.f, 0.f};
  float B8[8] = {}, L8[8] = {};

  const float* base = cls + (size_t)n * 72 * 512;
  float4 xa0, xa1, xb0, xb1, ya0, ya1, yb0, yb1;
  {
    const float* sA = base + (size_t)w * 512;
    const float* sB = base + (size_t)(w + 4) * 512;
    xa0 = *(const float4*)(sA + j0); xa1 = *(const float4*)(sA + j1);
    xb0 = *(const float4*)(sB + j0); xb1 = *(const float4*)(sB + j1);
    const float* sA1 = base + (size_t)(w + 8) * 512;
    const float* sB1 = base + (size_t)(w + 12) * 512;
    ya0 = *(const float4*)(sA1 + j0); ya1 = *(const float4*)(sA1 + j1);
    yb0 = *(const float4*)(sB1 + j0); yb1 = *(const float4*)(sB1 + j1);
  }
  for (int p = 0; p < 9; ++p) {
    float4 za0, za1, zb0, zb1;
    const bool more2 = (p + 2 < 9);
    if (more2) {
      const float* sA = base + (size_t)(w + 8 * (p + 2)) * 512;
      const float* sB = base + (size_t)(w + 4 + 8 * (p + 2)) * 512;
      za0 = *(const float4*)(sA + j0); za1 = *(const float4*)(sA + j1);
      zb0 = *(const float4*)(sB + j0); zb1 = *(const float4*)(sB + j1);
    }
    f32x2 qa[4], qb[4];
    split4(xa0, qa[0], qa[1]); split4(xa1, qa[2], qa[3]);
    split4(xb0, qb[0], qb[1]); split4(xb1, qb[2], qb[3]);
    f32x2 sa2 = qa[0] + qa[1] + qa[2] + qa[3];
    f32x2 ssa2 = qa[0] * qa[0] + qa[1] * qa[1] + qa[2] * qa[2] + qa[3] * qa[3];
    f32x2 sb2 = qb[0] + qb[1] + qb[2] + qb[3];
    f32x2 ssb2 = qb[0] * qb[0] + qb[1] * qb[1] + qb[2] * qb[2] + qb[3] * qb[3];
    float sa = sa2[0] + sa2[1], ssa = ssa2[0] + ssa2[1];
    float sb = sb2[0] + sb2[1], ssb = ssb2[0] + ssb2[1];
    float v8a[8], v8b[8];
#pragma unroll
    for (int hh = 0; hh < 8; ++hh) {
      const float4 w0 = *(const float4*)&gw_s[hh][j0];
      const float4 w1 = *(const float4*)&gw_s[hh][j1];
      f32x2 g0, g1, g2, g3;
      split4(w0, g0, g1); split4(w1, g2, g3);
      f32x2 da = qa[0] * g0 + qa[1] * g1 + qa[2] * g2 + qa[3] * g3;
      f32x2 db = qb[0] * g0 + qb[1] * g1 + qb[2] * g2 + qb[3] * g3;
      v8a[hh] = da[0] + da[1];
      v8b[hh] = db[0] + db[1];
    }
    sa = wsum(sa); ssa = wsum(ssa); sb = wsum(sb); ssb = wsum(ssb);
    const float meanA = sa * (1.f / 512.f);
    const float rstdA = rsqrtf(ssa * (1.f / 512.f) - meanA * meanA + 1e-5f);
    const float meanB = sb * (1.f / 512.f);
    const float rstdB = rsqrtf(ssb * (1.f / 512.f) - meanB * meanB + 1e-5f);
    const float za = fold8(v8a, lane);
    const float zb = fold8(v8b, lane);
    const float zfa = rstdA * 0.125f * (za - meanA * sg_r) + bw8_r;
    const float zfb = rstdB * 0.125f * (zb - meanB * sg_r) + bw8_r;
    const int kA = 5 + w + 8 * p;
    if (lane < 8) {
      sc_s[lane][kA] = zfa; sc_s[lane][kA + 4] = zfb;
      es_s[w][0][lane] = __expf(zfa);
      es_s[w][1][lane] = __expf(zfb);
    }
    __builtin_amdgcn_wave_barrier();
    const float4 ea0 = *(const float4*)&es_s[w][0][0];
    const float4 ea1 = *(const float4*)&es_s[w][0][4];
    const float4 eb0 = *(const float4*)&es_s[w][1][0];
    const float4 eb1 = *(const float4*)&es_s[w][1][4];
    const float esa[8] = {ea0.x, ea0.y, ea0.z, ea0.w, ea1.x, ea1.y, ea1.z, ea1.w};
    const float esb[8] = {eb0.x, eb0.y, eb0.z, eb0.w, eb1.x, eb1.y, eb1.z, eb1.w};
#pragma unroll
    for (int hh = 0; hh < 8; ++hh) {
      const float erA = esa[hh] * rstdA;
      const float erB = esb[hh] * rstdB;
      const f32x2 eA = f32x2{erA, erA};
      const f32x2 eB = f32x2{erB, erB};
      A2[hh][0] += eA * qa[0]; A2[hh][1] += eA * qa[1];
      A2[hh][2] += eA * qa[2]; A2[hh][3] += eA * qa[3];
      A2[hh][0] += eB * qb[0]; A2[hh][1] += eB * qb[1];
      A2[hh][2] += eB * qb[2]; A2[hh][3] += eB * qb[3];
      B8[hh] += erA * meanA + erB * meanB;
      L8[hh] += esa[hh] + esb[hh];
    }
    xa0 = ya0; xa1 = ya1; xb0 = yb0; xb1 = yb1;
    if (more2) { ya0 = za0; ya1 = za1; yb0 = zb0; yb1 = zb1; }
  }
  if (lane == 0)
#pragma unroll
    for (int hh = 0; hh < 8; ++hh) {
      wstatB[w][hh] = B8[hh]; wstatL[w][hh] = L8[hh];
    }
  __syncthreads();

  // ---- pass-1 softmax over 77 -> head-mean of first 5 -> attr
  for (int hh = w; hh < 8; hh += 4) {
    const float v0 = sc_s[hh][lane];
    const float v1 = (lane + 64 < 77) ? sc_s[hh][lane + 64] : -1e30f;
    const float mx = wmaxr(fmaxf(v0, v1));
    const float e0 = __expf(v0 - mx);
    const float e1 = (lane + 64 < 77) ? __expf(v1 - mx) : 0.f;
    const float S = wsum(e0 + e1);
    if (lane < 5) ah_s[hh][lane] = e0 / S;
  }
  __syncthreads();
  if (tid == 0) {
    float m[5], mx = -1e30f;
#pragma unroll
    for (int p = 0; p < 5; ++p) {
      float acc = 0.f;
      for (int hh = 0; hh < 8; ++hh) acc += ah_s[hh][p];
      m[p] = acc * 0.125f;
      mx = fmaxf(mx, m[p]);
    }
    float e[5], S = 0.f;
#pragma unroll
    for (int p = 0; p < 5; ++p) { e[p] = __expf(m[p] - mx); S += e[p]; }
#pragma unroll
    for (int p = 0; p < 5; ++p) attr_s[p] = e[p] / S;
  }
  __syncthreads();

  // ---- stage C: scaled ctx rows (global reads) -> h2 (bf16 LDS) + sc2
  for (int k = w; k < 5; k += 4) {
    const float c = attr_s[k];
    const float* src = ctx + ((size_t)n * 5 + k) * 512;
    float4 x0 = *(const float4*)(src + j0);
    float4 x1 = *(const float4*)(src + j1);
    x0.x *= c; x0.y *= c; x0.z *= c; x0.w *= c;
    x1.x *= c; x1.y *= c; x1.z *= c; x1.w *= c;
    f32x2 q[4];
    split4(x0, q[0], q[1]); split4(x1, q[2], q[3]);
    f32x2 s2v = q[0] + q[1] + q[2] + q[3];
    f32x2 ss2 = q[0] * q[0] + q[1] * q[1] + q[2] * q[2] + q[3] * q[3];
    float s  = s2v[0] + s2v[1];
    float ss = ss2[0] + ss2[1];
    float v8[8];
#pragma unroll
    for (int hh = 0; hh < 8; ++hh) {
      const float4 w0 = *(const float4*)&gw_s[hh][j0];
      const float4 w1 = *(const float4*)&gw_s[hh][j1];
      f32x2 g0, g1, g2, g3;
      split4(w0, g0, g1); split4(w1, g2, g3);
      f32x2 d = q[0] * g0 + q[1] * g1 + q[2] * g2 + q[3] * g3;
      v8[hh] = d[0] + d[1];
    }
    s = wsum(s); ss = wsum(ss);
    const float mean = s * (1.f / 512.f);
    const float rstd = rsqrtf(ss * (1.f / 512.f) - mean * mean + 1e-5f);
    {
      const float4 gg0 = *(const float4*)&g_s[j0];
      const float4 bb0 = *(const float4*)&b_s[j0];
      const float4 gg1 = *(const float4*)&g_s[j1];
      const float4 bb1 = *(const float4*)&b_s[j1];
      s16x4 o0, o1;
      o0[0] = f2bf((x0.x - mean) * rstd * gg0.x + bb0.x);
      o0[1] = f2bf((x0.y - mean) * rstd * gg0.y + bb0.y);
      o0[2] = f2bf((x0.z - mean) * rstd * gg0.z + bb0.z);
      o0[3] = f2bf((x0.w - mean) * rstd * gg0.w + bb0.w);
      o1[0] = f2bf((x1.x - mean) * rstd * gg1.x + bb1.x);
      o1[1] = f2bf((x1.y - mean) * rstd * gg1.y + bb1.y);
      o1[2] = f2bf((x1.z - mean) * rstd * gg1.z + bb1.z);
      o1[3] = f2bf((x1.w - mean) * rstd * gg1.w + bb1.w);
      *(s16x4*)&h2_s[k][j0] = o0;
      *(s16x4*)&h2_s[k][j1] = o1;
    }
    const float z = fold8(v8, lane);
    const float zf = rstd * 0.125f * (z - mean * sg_r) + bw8_r;
    if (lane < 8) sc2_s[lane][k] = zf;
  }
  __syncthreads();

  // ---- cross-wave A combine into gw_s region (float4)
  for (int wv = 0; wv < 4; ++wv) {
    if (w == wv) {
#pragma unroll
      for (int hh = 0; hh < 8; ++hh) {
        float4* p0 = (float4*)&gw_s[hh][j0];
        float4* p1 = (float4*)&gw_s[hh][j1];
        const float4 a0 = make_float4(A2[hh][0][0], A2[hh][0][1],
                                      A2[hh][1][0], A2[hh][1][1]);
        const float4 a1 = make_float4(A2[hh][2][0], A2[hh][2][1],
                                      A2[hh][3][0], A2[hh][3][1]);
        if (wv == 0) { *p0 = a0; *p1 = a1; }
        else {
          float4 v0 = *p0, v1 = *p1;
          v0.x += a0.x; v0.y += a0.y; v0.z += a0.z; v0.w += a0.w;
          v1.x += a1.x; v1.y += a1.y; v1.z += a1.z; v1.w += a1.w;
          *p0 = v0; *p1 = v1;
        }
      }
    }
    __syncthreads();
  }

  if (tid < 8) {
    float Bt = 0.f, Lt = 0.f;
    for (int wv = 0; wv < 4; ++wv) { Bt += wstatB[wv][tid]; Lt += wstatL[wv][tid]; }
    float den = Lt;
#pragma unroll
    for (int k = 0; k < 5; ++k) {
      const float e = __expf(sc2_s[tid][k]);
      e2_s[tid][k] = e; den += e;
    }
    Bt_s[tid] = Bt; Lt_s[tid] = Lt; inv_s[tid] = 1.f / den;
  }
  __syncthreads();

  // ---- u[hh][j] (bf16) = ((g*(A-B) + b*L + sum_k e2*h2) / den)
  __hip_bfloat16* dst = u_out + (size_t)n * 4096;
  for (int bidx = tid * 4; bidx < 4096; bidx += 1024) {
    const int hh = bidx >> 9, j = bidx & 511;
    const float4 a4 = *(const float4*)&gw_s[hh][j];
    const float4 g4 = *(const float4*)&g_s[j];
    const float4 b4 = *(const float4*)&b_s[j];
    const float Bt = Bt_s[hh], Lt = Lt_s[hh];
    float v0 = (a4.x - Bt) * g4.x + Lt * b4.x;
    float v1 = (a4.y - Bt) * g4.y + Lt * b4.y;
    float v2 = (a4.z - Bt) * g4.z + Lt * b4.z;
    float v3 = (a4.w - Bt) * g4.w + Lt * b4.w;
#pragma unroll
    for (int k = 0; k < 5; ++k) {
      const s16x4 hq = *(const s16x4*)&h2_s[k][j];
      const float e = e2_s[hh][k];
      v0 += e * bfs2f(hq[0]); v1 += e * bfs2f(hq[1]);
      v2 += e * bfs2f(hq[2]); v3 += e * bfs2f(hq[3]);
    }
    const float iv = inv_s[hh];
    s16x4 o;
    o[0] = f2bf(v0 * iv); o[1] = f2bf(v1 * iv);
    o[2] = f2bf(v2 * iv); o[3] = f2bf(v3 * iv);
    *(s16x4*)&dst[bidx] = o;
  }
}

// ---------------------------------------------------------------------------
extern "C" void kernel_launch(void* const* d_in, const int* in_sizes, int n_in,
                              void* d_out, int out_size, void* d_ws, size_t ws_size,
                              hipStream_t stream)
{
  const float* images = (const float*)d_in[0];
  const float* W_img  = (const float*)d_in[1];
  const float* ctx    = (const float*)d_in[2];
  const float* cls    = (const float*)d_in[3];
  const float* ln_g   = (const float*)d_in[4];
  const float* ln_b   = (const float*)d_in[5];
  const float* Wq     = (const float*)d_in[6];
  const float* Wk     = (const float*)d_in[7];
  const float* Wv     = (const float*)d_in[8];
  const float* Wo     = (const float*)d_in[9];
  const float* tproj  = (const float*)d_in[10];
  const float* lscale = (const float*)d_in[11];

  __hip_bfloat16* wtu = (__hip_bfloat16*)d_ws;  // wt -> u (bf16, in place)
  float* fws  = (float*)d_ws;
  float* img  = fws + 2048000;
  float* hlO  = img + 131072;       // O
  float* qo2  = hlO + 512000;       // q -> out2
  float* txt  = fws;                // alias over dead u region
  (void)in_sizes; (void)n_in; (void)out_size; (void)ws_size;

  // 1) image embedding (bf16 MFMA), unnormalized (logits_k normalizes)
  gemm_mfma_k<0,0,0,0><<<dim3(8,4,1),256,0,stream>>>(images,768,0, W_img,512,0,
      img,512,0, nullptr,0, 256,512,768);

  // 2) q = LN(cls_last) @ Wq  (LN fused into staging)
  gemm_mfma_lnA_k<<<dim3(8,16),256,0,stream>>>(cls + 71*512, 72*512,
      ln_g, ln_b, Wq,512, qo2,512, 1000,512,512);

  // 3) wt = per-head q @ Wk^T  -> bf16 (grid already 1024, keep 64-tile)
  gemm_mfma_k<1,0,0,1><<<dim3(8,16,8),256,0,stream>>>(qo2,512,64, Wk,512,64,
      wtu,4096,512, nullptr,0, 1000,512,64);

  // 4+5) fused pass1+pass2 sweep -> u bf16 (in place over wt)
  fused_sweep_kernel<<<1000,256,0,stream>>>(ctx, cls, ln_g, ln_b, wtu, wtu);

  // 6) O = per-head u @ Wv  (32-tile MFMA -> 256 blocks, A read as bf16)
  gemm32_mfma_k<0,1><<<dim3(1,32,8),256,0,stream>>>(wtu,4096,512, Wv,512,64,
      hlO,512,64, nullptr,0, 1000,64,512);

  // 7) out2 = cls_last + O @ Wo ; txt = out2 @ text_proj  (32-tile MFMA)
  gemm32_mfma_k<1,0><<<dim3(8,32,1),256,0,stream>>>(hlO,512,0, Wo,512,0,
      qo2,512,0, cls + 71*512, 72*512, 1000,512,512);
  gemm32_mfma_k<0,0><<<dim3(8,32,1),256,0,stream>>>(qo2,512,0, tproj,512,0,
      txt,512,0, nullptr,0, 1000,512,512);

  // 8) logits = exp(ls) * (img/|img|) @ (txt/|txt|)^T  (norms fused, f32)
  logits_k<<<dim3(16,8),256,0,stream>>>(img,512, txt,512,
      (float*)d_out,1000, lscale, 256,1000,512);
}

// Round 17
// 133.358 us; speedup vs baseline: 1.3141x; 1.1227x over previous
//
#include <hip/hip_runtime.h>
#include <hip/hip_bf16.h>

#define DEV static __device__ __forceinline__

typedef __attribute__((ext_vector_type(8))) short bf16x8;
typedef __attribute__((ext_vector_type(4))) short s16x4;
typedef __attribute__((ext_vector_type(4))) float f32x4;
typedef __attribute__((ext_vector_type(2))) float f32x2;

DEV float wsum(float v) {
  v += __shfl_xor(v, 1);  v += __shfl_xor(v, 2);  v += __shfl_xor(v, 4);
  v += __shfl_xor(v, 8);  v += __shfl_xor(v, 16); v += __shfl_xor(v, 32);
  return v;
}
DEV float wmaxr(float v) {
  v = fmaxf(v, __shfl_xor(v, 1));  v = fmaxf(v, __shfl_xor(v, 2));
  v = fmaxf(v, __shfl_xor(v, 4));  v = fmaxf(v, __shfl_xor(v, 8));
  v = fmaxf(v, __shfl_xor(v, 16)); v = fmaxf(v, __shfl_xor(v, 32));
  return v;
}
DEV short f2bf(float x) {
  __hip_bfloat16 h = __float2bfloat16(x);
  return *reinterpret_cast<short*>(&h);
}
DEV float bf2f(unsigned int u) {
  const unsigned int x = u << 16;
  return __uint_as_float(x);
}
DEV float bfs2f(short s) {
  const unsigned int x = ((unsigned int)(unsigned short)s) << 16;
  return __uint_as_float(x);
}
DEV void split4(const float4& v, f32x2& lo, f32x2& hi) {
  lo = f32x2{v.x, v.y}; hi = f32x2{v.z, v.w};
}

// Fold-reduce 8 per-lane values across 64 lanes -> full sum of head (lane&7).
DEV float fold8(const float v[8], int lane) {
  float w4[4];
#pragma unroll
  for (int j = 0; j < 4; ++j) {
    const float mine  = (lane & 1) ? v[2 * j + 1] : v[2 * j];
    const float other = (lane & 1) ? v[2 * j]     : v[2 * j + 1];
    w4[j] = mine + __shfl_xor(other, 1);
  }
  float u2[2];
#pragma unroll
  for (int j = 0; j < 2; ++j) {
    const float mine  = (lane & 2) ? w4[2 * j + 1] : w4[2 * j];
    const float other = (lane & 2) ? w4[2 * j]     : w4[2 * j + 1];
    u2[j] = mine + __shfl_xor(other, 2);
  }
  const float mine  = (lane & 4) ? u2[1] : u2[0];
  const float other = (lane & 4) ? u2[0] : u2[1];
  float z = mine + __shfl_xor(other, 4);
  z += __shfl_xor(z, 8); z += __shfl_xor(z, 16); z += __shfl_xor(z, 32);
  return z;
}

// ---------------------------------------------------------------------------
// Unified bf16 MFMA GEMM: 64x64 tile, depth-2 register prefetch + LDS dbuf.
// (HW-validated rounds 12-16; used for wt GEMM)
// ---------------------------------------------------------------------------
template <int TRANSB, int ADDD, int ABF16, int OUTBF16>
__global__ __launch_bounds__(256) void gemm_mfma_k(
    const void* __restrict__ Av, int lda, long long bsA,
    const float* __restrict__ B, int ldb, long long bsB,
    void* __restrict__ Cv, int ldc, long long bsC,
    const float* __restrict__ D, long long ldd,
    int M, int N, int K)
{
  const float* Af = (const float*)Av + (ABF16 ? 0 : (size_t)blockIdx.z * bsA);
  const short* Ah = (const short*)Av + (ABF16 ? (size_t)blockIdx.z * bsA : 0);
  B += (size_t)blockIdx.z * bsB;
  const int m0 = blockIdx.y * 64, n0 = blockIdx.x * 64;
  const int tid = threadIdx.x;
  const int w = tid >> 6, lane = tid & 63;
  const int wr = w >> 1, wc = w & 1;
  __shared__ __attribute__((aligned(16))) short As[2][64][40];
  __shared__ __attribute__((aligned(16))) short Bs[2][64][40];
  f32x4 acc[2][2] = {};

  const int ar = tid >> 2, akc = (tid & 3) * 8;
  const int br = tid >> 3, bnc = (tid & 7) * 8;
  const bool arv = (m0 + ar < M);
  const int rbase = wr * 32 + (lane & 15);
  const int cbase = wc * 32 + (lane & 15);
  const int kb = (lane >> 4) * 8;

  auto gload = [&](int k0, float4& a0, float4& a1, bf16x8& ah,
                   float4& b0, float4& b1) {
    if (ABF16) {
      ah = bf16x8{};
      if (arv) ah = *(const bf16x8*)(Ah + (size_t)(m0 + ar) * lda + k0 + akc);
    } else {
      a0 = make_float4(0.f, 0.f, 0.f, 0.f); a1 = a0;
      if (arv) {
        a0 = *(const float4*)(Af + (size_t)(m0 + ar) * lda + k0 + akc);
        a1 = *(const float4*)(Af + (size_t)(m0 + ar) * lda + k0 + akc + 4);
      }
    }
    if (TRANSB) {
      b0 = *(const float4*)(B + (size_t)(n0 + ar) * ldb + k0 + akc);
      b1 = *(const float4*)(B + (size_t)(n0 + ar) * ldb + k0 + akc + 4);
    } else {
      b0 = *(const float4*)(B + (size_t)(k0 + br) * ldb + n0 + bnc);
      b1 = *(const float4*)(B + (size_t)(k0 + br) * ldb + n0 + bnc + 4);
    }
  };
  auto stage = [&](int buf, const float4& a0, const float4& a1, const bf16x8& ah,
                   const float4& b0, const float4& b1) {
    if (ABF16) {
      *(bf16x8*)&As[buf][ar][akc] = ah;
    } else {
      bf16x8 av;
      av[0] = f2bf(a0.x); av[1] = f2bf(a0.y); av[2] = f2bf(a0.z); av[3] = f2bf(a0.w);
      av[4] = f2bf(a1.x); av[5] = f2bf(a1.y); av[6] = f2bf(a1.z); av[7] = f2bf(a1.w);
      *(bf16x8*)&As[buf][ar][akc] = av;
    }
    if (TRANSB) {
      bf16x8 bv;
      bv[0] = f2bf(b0.x); bv[1] = f2bf(b0.y); bv[2] = f2bf(b0.z); bv[3] = f2bf(b0.w);
      bv[4] = f2bf(b1.x); bv[5] = f2bf(b1.y); bv[6] = f2bf(b1.z); bv[7] = f2bf(b1.w);
      *(bf16x8*)&Bs[buf][ar][akc] = bv;
    } else {
      Bs[buf][bnc + 0][br] = f2bf(b0.x); Bs[buf][bnc + 1][br] = f2bf(b0.y);
      Bs[buf][bnc + 2][br] = f2bf(b0.z); Bs[buf][bnc + 3][br] = f2bf(b0.w);
      Bs[buf][bnc + 4][br] = f2bf(b1.x); Bs[buf][bnc + 5][br] = f2bf(b1.y);
      Bs[buf][bnc + 6][br] = f2bf(b1.z); Bs[buf][bnc + 7][br] = f2bf(b1.w);
    }
  };
  auto compute = [&](int buf) {
    bf16x8 af0 = *(const bf16x8*)&As[buf][rbase][kb];
    bf16x8 af1 = *(const bf16x8*)&As[buf][rbase + 16][kb];
    bf16x8 bf0 = *(const bf16x8*)&Bs[buf][cbase][kb];
    bf16x8 bf1 = *(const bf16x8*)&Bs[buf][cbase + 16][kb];
    acc[0][0] = __builtin_amdgcn_mfma_f32_16x16x32_bf16(af0, bf0, acc[0][0], 0, 0, 0);
    acc[0][1] = __builtin_amdgcn_mfma_f32_16x16x32_bf16(af0, bf1, acc[0][1], 0, 0, 0);
    acc[1][0] = __builtin_amdgcn_mfma_f32_16x16x32_bf16(af1, bf0, acc[1][0], 0, 0, 0);
    acc[1][1] = __builtin_amdgcn_mfma_f32_16x16x32_bf16(af1, bf1, acc[1][1], 0, 0, 0);
  };

  float4 a0A, a1A, b0A, b1A, a0B, a1B, b0B, b1B;
  bf16x8 ahA = {}, ahB = {};
  gload(0, a0A, a1A, ahA, b0A, b1A);
  gload(32, a0B, a1B, ahB, b0B, b1B);
  for (int k0 = 0; k0 < K; k0 += 64) {
    stage(0, a0A, a1A, ahA, b0A, b1A);
    if (k0 + 64 < K) gload(k0 + 64, a0A, a1A, ahA, b0A, b1A);
    __syncthreads();
    compute(0);
    stage(1, a0B, a1B, ahB, b0B, b1B);
    if (k0 + 96 < K) gload(k0 + 96, a0B, a1B, ahB, b0B, b1B);
    __syncthreads();
    compute(1);
  }

  const size_t cb = (size_t)blockIdx.z * (size_t)bsC;
#pragma unroll
  for (int mi = 0; mi < 2; ++mi)
#pragma unroll
    for (int ni = 0; ni < 2; ++ni)
#pragma unroll
      for (int r = 0; r < 4; ++r) {
        const int row = m0 + wr * 32 + mi * 16 + (lane >> 4) * 4 + r;
        const int col = n0 + wc * 32 + ni * 16 + (lane & 15);
        if (row < M) {
          float v = acc[mi][ni][r];
          if (ADDD) v += D[(size_t)row * ldd + col];
          if (OUTBF16)
            ((__hip_bfloat16*)Cv)[cb + (size_t)row * ldc + col] = __float2bfloat16(v);
          else
            ((float*)Cv)[cb + (size_t)row * ldc + col] = v;
        }
      }
}

// ---------------------------------------------------------------------------
// 32x64-tile bf16 MFMA GEMM (round-16, HW-validated; img, O, Wo, tproj).
// ---------------------------------------------------------------------------
template <int ADDD, int ABF16>
__global__ __launch_bounds__(256) void gemm32_mfma_k(
    const void* __restrict__ Av, int lda, long long bsA,
    const float* __restrict__ B, int ldb, long long bsB,
    float* __restrict__ C, int ldc, long long bsC,
    const float* __restrict__ D, long long ldd,
    int M, int N, int K)
{
  const float* Af = (const float*)Av + (ABF16 ? 0 : (size_t)blockIdx.z * bsA);
  const short* Ah = (const short*)Av + (ABF16 ? (size_t)blockIdx.z * bsA : 0);
  B += (size_t)blockIdx.z * bsB;
  const int m0 = blockIdx.y * 32, n0 = blockIdx.x * 64;
  const int tid = threadIdx.x;
  const int w = tid >> 6, lane = tid & 63;
  const int wr = w >> 1, wc = w & 1;
  __shared__ __attribute__((aligned(16))) short As[2][32][40];
  __shared__ __attribute__((aligned(16))) short Bs[2][64][40];
  f32x4 acc[2] = {};

  const int ar = tid >> 3, akc = (tid & 7) * 4;
  const int br = tid >> 3, bnc = (tid & 7) * 8;
  const bool arv = (m0 + ar < M);
  const int rbase = wr * 16 + (lane & 15);
  const int cbase = wc * 32 + (lane & 15);
  const int kb = (lane >> 4) * 8;

  auto gload = [&](int k0, float4& a0, s16x4& ah, float4& b0, float4& b1) {
    if (ABF16) {
      ah = s16x4{};
      if (arv) ah = *(const s16x4*)(Ah + (size_t)(m0 + ar) * lda + k0 + akc);
    } else {
      a0 = make_float4(0.f, 0.f, 0.f, 0.f);
      if (arv) a0 = *(const float4*)(Af + (size_t)(m0 + ar) * lda + k0 + akc);
    }
    b0 = *(const float4*)(B + (size_t)(k0 + br) * ldb + n0 + bnc);
    b1 = *(const float4*)(B + (size_t)(k0 + br) * ldb + n0 + bnc + 4);
  };
  auto stage = [&](int buf, const float4& a0, const s16x4& ah,
                   const float4& b0, const float4& b1) {
    if (ABF16) {
      *(s16x4*)&As[buf][ar][akc] = ah;
    } else {
      s16x4 av;
      av[0] = f2bf(a0.x); av[1] = f2bf(a0.y);
      av[2] = f2bf(a0.z); av[3] = f2bf(a0.w);
      *(s16x4*)&As[buf][ar][akc] = av;
    }
    Bs[buf][bnc + 0][br] = f2bf(b0.x); Bs[buf][bnc + 1][br] = f2bf(b0.y);
    Bs[buf][bnc + 2][br] = f2bf(b0.z); Bs[buf][bnc + 3][br] = f2bf(b0.w);
    Bs[buf][bnc + 4][br] = f2bf(b1.x); Bs[buf][bnc + 5][br] = f2bf(b1.y);
    Bs[buf][bnc + 6][br] = f2bf(b1.z); Bs[buf][bnc + 7][br] = f2bf(b1.w);
  };
  auto compute = [&](int buf) {
    bf16x8 af  = *(const bf16x8*)&As[buf][rbase][kb];
    bf16x8 bf0 = *(const bf16x8*)&Bs[buf][cbase][kb];
    bf16x8 bf1 = *(const bf16x8*)&Bs[buf][cbase + 16][kb];
    acc[0] = __builtin_amdgcn_mfma_f32_16x16x32_bf16(af, bf0, acc[0], 0, 0, 0);
    acc[1] = __builtin_amdgcn_mfma_f32_16x16x32_bf16(af, bf1, acc[1], 0, 0, 0);
  };

  float4 a0A, b0A, b1A, a0B, b0B, b1B;
  s16x4 ahA = {}, ahB = {};
  gload(0, a0A, ahA, b0A, b1A);
  gload(32, a0B, ahB, b0B, b1B);
  for (int k0 = 0; k0 < K; k0 += 64) {
    stage(0, a0A, ahA, b0A, b1A);
    if (k0 + 64 < K) gload(k0 + 64, a0A, ahA, b0A, b1A);
    __syncthreads();
    compute(0);
    stage(1, a0B, ahB, b0B, b1B);
    if (k0 + 96 < K) gload(k0 + 96, a0B, ahB, b0B, b1B);
    __syncthreads();
    compute(1);
  }

  const size_t cb = (size_t)blockIdx.z * (size_t)bsC;
#pragma unroll
  for (int ni = 0; ni < 2; ++ni)
#pragma unroll
    for (int r = 0; r < 4; ++r) {
      const int row = m0 + wr * 16 + (lane >> 4) * 4 + r;
      const int col = n0 + wc * 32 + ni * 16 + (lane & 15);
      if (row < M) {
        float v = acc[ni][r];
        if (ADDD) v += D[(size_t)row * ldd + col];
        C[cb + (size_t)row * ldc + col] = v;
      }
    }
}

// ---------------------------------------------------------------------------
// NEW: logits MFMA — 32x64 tile, B TRANSB (txt rows), L2 norms of A rows and
// B rows accumulated from the f32 values at load time (each 32-k slice is
// loaded exactly once by the depth-2 schedule -> norms exact); only the dot
// runs in bf16. C = exp(alpha) * (A_m . B_n) / (|A_m||B_n|).
// ---------------------------------------------------------------------------
__global__ __launch_bounds__(256) void logits_mfma_k(
    const float* __restrict__ A, int lda,
    const float* __restrict__ B, int ldb,
    float* __restrict__ C, int ldc,
    const float* __restrict__ alpha_ptr,
    int M, int N, int K)
{
  const int m0 = blockIdx.y * 32, n0 = blockIdx.x * 64;
  const int tid = threadIdx.x;
  const int w = tid >> 6, lane = tid & 63;
  const int wr = w >> 1, wc = w & 1;
  __shared__ __attribute__((aligned(16))) short As[2][32][40];
  __shared__ __attribute__((aligned(16))) short Bs[2][64][40];
  __shared__ float nA[32], nB[64];
  f32x4 acc[2] = {};
  float ssA = 0.f, ssB = 0.f;

  const int arA = tid >> 3, akcA = (tid & 7) * 4;   // A: 32 rows x 32 k
  const int arB = tid >> 2, akcB = (tid & 3) * 8;   // B^T: 64 rows x 32 k
  const bool bv_ = (n0 + arB < N);                  // M=256: A rows always valid
  const int rbase = wr * 16 + (lane & 15);
  const int cbase = wc * 32 + (lane & 15);
  const int kb = (lane >> 4) * 8;

  auto gload = [&](int k0, float4& a0, float4& b0, float4& b1) {
    a0 = *(const float4*)(A + (size_t)(m0 + arA) * lda + k0 + akcA);
    b0 = make_float4(0.f, 0.f, 0.f, 0.f); b1 = b0;
    if (bv_) {
      b0 = *(const float4*)(B + (size_t)(n0 + arB) * ldb + k0 + akcB);
      b1 = *(const float4*)(B + (size_t)(n0 + arB) * ldb + k0 + akcB + 4);
    }
    ssA += a0.x * a0.x + a0.y * a0.y + a0.z * a0.z + a0.w * a0.w;
    ssB += b0.x * b0.x + b0.y * b0.y + b0.z * b0.z + b0.w * b0.w
         + b1.x * b1.x + b1.y * b1.y + b1.z * b1.z + b1.w * b1.w;
  };
  auto stage = [&](int buf, const float4& a0, const float4& b0, const float4& b1) {
    s16x4 av;
    av[0] = f2bf(a0.x); av[1] = f2bf(a0.y);
    av[2] = f2bf(a0.z); av[3] = f2bf(a0.w);
    *(s16x4*)&As[buf][arA][akcA] = av;
    bf16x8 bvv;
    bvv[0] = f2bf(b0.x); bvv[1] = f2bf(b0.y); bvv[2] = f2bf(b0.z); bvv[3] = f2bf(b0.w);
    bvv[4] = f2bf(b1.x); bvv[5] = f2bf(b1.y); bvv[6] = f2bf(b1.z); bvv[7] = f2bf(b1.w);
    *(bf16x8*)&Bs[buf][arB][akcB] = bvv;
  };
  auto compute = [&](int buf) {
    bf16x8 af  = *(const bf16x8*)&As[buf][rbase][kb];
    bf16x8 bf0 = *(const bf16x8*)&Bs[buf][cbase][kb];
    bf16x8 bf1 = *(const bf16x8*)&Bs[buf][cbase + 16][kb];
    acc[0] = __builtin_amdgcn_mfma_f32_16x16x32_bf16(af, bf0, acc[0], 0, 0, 0);
    acc[1] = __builtin_amdgcn_mfma_f32_16x16x32_bf16(af, bf1, acc[1], 0, 0, 0);
  };

  float4 a0A, b0A, b1A, a0B, b0B, b1B;
  gload(0, a0A, b0A, b1A);
  gload(32, a0B, b0B, b1B);
  for (int k0 = 0; k0 < K; k0 += 64) {
    stage(0, a0A, b0A, b1A);
    if (k0 + 64 < K) gload(k0 + 64, a0A, b0A, b1A);
    __syncthreads();
    compute(0);
    stage(1, a0B, b0B, b1B);
    if (k0 + 96 < K) gload(k0 + 96, a0B, b0B, b1B);
    __syncthreads();
    compute(1);
  }

  // norms: A row shared by 8 threads (tid = row*8+p); B row by 4 (tid = row*4+p)
  ssA += __shfl_xor(ssA, 1); ssA += __shfl_xor(ssA, 2); ssA += __shfl_xor(ssA, 4);
  if ((tid & 7) == 0) nA[arA] = rsqrtf(ssA);
  ssB += __shfl_xor(ssB, 1); ssB += __shfl_xor(ssB, 2);
  if ((tid & 3) == 0) nB[arB] = rsqrtf(ssB);
  __syncthreads();

  const float alpha = __expf(alpha_ptr[0]);
#pragma unroll
  for (int ni = 0; ni < 2; ++ni)
#pragma unroll
    for (int r = 0; r < 4; ++r) {
      const int rowl = wr * 16 + (lane >> 4) * 4 + r;
      const int coll = wc * 32 + ni * 16 + (lane & 15);
      const int col = n0 + coll;
      if (col < N)
        C[(size_t)(m0 + rowl) * ldc + col] = acc[ni][r] * alpha * nA[rowl] * nB[coll];
    }
}

// ---------------------------------------------------------------------------
// bf16 MFMA GEMM with LayerNorm fused on A (unchanged).
// ---------------------------------------------------------------------------
__global__ __launch_bounds__(256) void gemm_mfma_lnA_k(
    const float* __restrict__ A, long long lda,
    const float* __restrict__ g, const float* __restrict__ b,
    const float* __restrict__ B, int ldb,
    float* __restrict__ C, int ldc,
    int M, int N, int K)
{
  const int m0 = blockIdx.y * 64, n0 = blockIdx.x * 64;
  const int tid = threadIdx.x;
  const int w = tid >> 6, lane = tid & 63;
  const int wr = w >> 1, wc = w & 1;
  __shared__ __attribute__((aligned(16))) short As[2][64][40];
  __shared__ __attribute__((aligned(16))) short Bs[2][64][40];
  __shared__ __attribute__((aligned(16))) float g_s[512], b_s[512];
  __shared__ float mean_s[64], rstd_s[64];
  f32x4 acc[2][2] = {};

  if (tid < 128) ((float4*)g_s)[tid] = ((const float4*)g)[tid];
  else ((float4*)b_s)[tid - 128] = ((const float4*)b)[tid - 128];

  {
    const int r = tid >> 2, p = tid & 3;
    float s = 0.f, ss = 0.f;
    if (m0 + r < M) {
      const float4* src = (const float4*)(A + (size_t)(m0 + r) * lda + p * 128);
#pragma unroll 8
      for (int i = 0; i < 32; ++i) {
        const float4 v = src[i];
        s += v.x + v.y + v.z + v.w;
        ss += v.x * v.x + v.y * v.y + v.z * v.z + v.w * v.w;
      }
    }
    s += __shfl_xor(s, 1);  s += __shfl_xor(s, 2);
    ss += __shfl_xor(ss, 1); ss += __shfl_xor(ss, 2);
    if (p == 0) {
      const float mean = s * (1.f / 512.f);
      mean_s[r] = mean;
      rstd_s[r] = rsqrtf(ss * (1.f / 512.f) - mean * mean + 1e-5f);
    }
  }
  __syncthreads();

  const int ar = tid >> 2, akc = (tid & 3) * 8;
  const int br = tid >> 3, bnc = (tid & 7) * 8;
  const bool arv = (m0 + ar < M);
  const int rbase = wr * 32 + (lane & 15);
  const int cbase = wc * 32 + (lane & 15);
  const int kb = (lane >> 4) * 8;

  auto gload = [&](int k0, float4& a0, float4& a1, float4& b0, float4& b1) {
    a0 = make_float4(0.f, 0.f, 0.f, 0.f); a1 = a0;
    if (arv) {
      a0 = *(const float4*)(A + (size_t)(m0 + ar) * lda + k0 + akc);
      a1 = *(const float4*)(A + (size_t)(m0 + ar) * lda + k0 + akc + 4);
    }
    b0 = *(const float4*)(B + (size_t)(k0 + br) * ldb + n0 + bnc);
    b1 = *(const float4*)(B + (size_t)(k0 + br) * ldb + n0 + bnc + 4);
  };
  auto stage = [&](int buf, int k0, const float4& a0, const float4& a1,
                   const float4& b0, const float4& b1) {
    const float mn = mean_s[ar], rs = rstd_s[ar];
    const int kc = k0 + akc;
    bf16x8 av;
    av[0] = f2bf((a0.x - mn) * rs * g_s[kc + 0] + b_s[kc + 0]);
    av[1] = f2bf((a0.y - mn) * rs * g_s[kc + 1] + b_s[kc + 1]);
    av[2] = f2bf((a0.z - mn) * rs * g_s[kc + 2] + b_s[kc + 2]);
    av[3] = f2bf((a0.w - mn) * rs * g_s[kc + 3] + b_s[kc + 3]);
    av[4] = f2bf((a1.x - mn) * rs * g_s[kc + 4] + b_s[kc + 4]);
    av[5] = f2bf((a1.y - mn) * rs * g_s[kc + 5] + b_s[kc + 5]);
    av[6] = f2bf((a1.z - mn) * rs * g_s[kc + 6] + b_s[kc + 6]);
    av[7] = f2bf((a1.w - mn) * rs * g_s[kc + 7] + b_s[kc + 7]);
    *(bf16x8*)&As[buf][ar][akc] = av;
    Bs[buf][bnc + 0][br] = f2bf(b0.x); Bs[buf][bnc + 1][br] = f2bf(b0.y);
    Bs[buf][bnc + 2][br] = f2bf(b0.z); Bs[buf][bnc + 3][br] = f2bf(b0.w);
    Bs[buf][bnc + 4][br] = f2bf(b1.x); Bs[buf][bnc + 5][br] = f2bf(b1.y);
    Bs[buf][bnc + 6][br] = f2bf(b1.z); Bs[buf][bnc + 7][br] = f2bf(b1.w);
  };
  auto compute = [&](int buf) {
    bf16x8 af0 = *(const bf16x8*)&As[buf][rbase][kb];
    bf16x8 af1 = *(const bf16x8*)&As[buf][rbase + 16][kb];
    bf16x8 bf0 = *(const bf16x8*)&Bs[buf][cbase][kb];
    bf16x8 bf1 = *(const bf16x8*)&Bs[buf][cbase + 16][kb];
    acc[0][0] = __builtin_amdgcn_mfma_f32_16x16x32_bf16(af0, bf0, acc[0][0], 0, 0, 0);
    acc[0][1] = __builtin_amdgcn_mfma_f32_16x16x32_bf16(af0, bf1, acc[0][1], 0, 0, 0);
    acc[1][0] = __builtin_amdgcn_mfma_f32_16x16x32_bf16(af1, bf0, acc[1][0], 0, 0, 0);
    acc[1][1] = __builtin_amdgcn_mfma_f32_16x16x32_bf16(af1, bf1, acc[1][1], 0, 0, 0);
  };

  float4 a0A, a1A, b0A, b1A, a0B, a1B, b0B, b1B;
  gload(0, a0A, a1A, b0A, b1A);
  gload(32, a0B, a1B, b0B, b1B);
  for (int k0 = 0; k0 < K; k0 += 64) {
    stage(0, k0, a0A, a1A, b0A, b1A);
    if (k0 + 64 < K) gload(k0 + 64, a0A, a1A, b0A, b1A);
    __syncthreads();
    compute(0);
    stage(1, k0 + 32, a0B, a1B, b0B, b1B);
    if (k0 + 96 < K) gload(k0 + 96, a0B, a1B, b0B, b1B);
    __syncthreads();
    compute(1);
  }

#pragma unroll
  for (int mi = 0; mi < 2; ++mi)
#pragma unroll
    for (int ni = 0; ni < 2; ++ni)
#pragma unroll
      for (int r = 0; r < 4; ++r) {
        const int row = m0 + wr * 32 + mi * 16 + (lane >> 4) * 4 + r;
        const int col = n0 + wc * 32 + ni * 16 + (lane & 15);
        if (row < M) C[(size_t)row * ldc + col] = acc[mi][ni][r];
      }
}

// ---------------------------------------------------------------------------
// FUSED sweep v8 (round-13/15/16 state — best known-good, ~89 us, frozen).
// ---------------------------------------------------------------------------
__global__ __launch_bounds__(256) void fused_sweep_kernel(
    const float* __restrict__ ctx, const float* __restrict__ cls,
    const float* __restrict__ g, const float* __restrict__ b,
    const __hip_bfloat16* __restrict__ wt, __hip_bfloat16* __restrict__ u_out)
{
  const int n = blockIdx.x, tid = threadIdx.x;
  const int w = tid >> 6, lane = tid & 63;
  __shared__ __attribute__((aligned(16))) float gw_s[8][512];
  __shared__ __attribute__((aligned(16))) float g_s[512], b_s[512];
  __shared__ __attribute__((aligned(16))) short h2_s[5][512];
  __shared__ float sc_s[8][80];
  __shared__ float sc2_s[8][5];
  __shared__ float ah_s[8][5];
  __shared__ float wstatB[4][8], wstatL[4][8];
  __shared__ float attr_s[5];
  __shared__ float Sgw_l[8], bw_l[8];
  __shared__ float Bt_s[8], Lt_s[8], inv_s[8];
  __shared__ float e2_s[8][5];
  __shared__ __attribute__((aligned(16))) float es_s[4][2][8];

  {
    const uint4* wsrc = (const uint4*)(wt + (size_t)n * 4096);
    float4* gwf = (float4*)&gw_s[0][0];
    for (int i = tid; i < 512; i += 256) {
      const uint4 v = wsrc[i];
      gwf[i * 2]     = make_float4(bf2f(v.x & 0xffffu), bf2f(v.x >> 16),
                                   bf2f(v.y & 0xffffu), bf2f(v.y >> 16));
      gwf[i * 2 + 1] = make_float4(bf2f(v.z & 0xffffu), bf2f(v.z >> 16),
                                   bf2f(v.w & 0xffffu), bf2f(v.w >> 16));
    }
    if (tid < 128) ((float4*)g_s)[tid] = ((const float4*)g)[tid];
    else ((float4*)b_s)[tid - 128] = ((const float4*)b)[tid - 128];
  }
  __syncthreads();

  for (int hh = w; hh < 8; hh += 4) {
    float s1 = 0.f, s2 = 0.f;
#pragma unroll
    for (int i = 0; i < 8; ++i) {
      const int j = lane + 64 * i;
      const float wv = gw_s[hh][j];
      const float gv = wv * g_s[j];
      s1 += gv; s2 += wv * b_s[j];
      gw_s[hh][j] = gv;
    }
    s1 = wsum(s1); s2 = wsum(s2);
    if (lane == 0) { Sgw_l[hh] = s1; bw_l[hh] = s2; }
  }
  __syncthreads();
  const float sg_r  = Sgw_l[lane & 7];
  const float bw8_r = bw_l[lane & 7] * 0.125f;
  const int j0 = lane * 4, j1 = lane * 4 + 256;

  // ---- stage A: 5 unscaled ctx rows (global reads) -> pass-1 scores
  for (int k = w; k < 5; k += 4) {
    const float* src = ctx + ((size_t)n * 5 + k) * 512;
    const float4 x0 = *(const float4*)(src + j0);
    const float4 x1 = *(const float4*)(src + j1);
    f32x2 q[4];
    split4(x0, q[0], q[1]); split4(x1, q[2], q[3]);
    f32x2 s2v = q[0] + q[1] + q[2] + q[3];
    f32x2 ss2 = q[0] * q[0] + q[1] * q[1] + q[2] * q[2] + q[3] * q[3];
    float s  = s2v[0] + s2v[1];
    float ss = ss2[0] + ss2[1];
    float v8[8];
#pragma unroll
    for (int hh = 0; hh < 8; ++hh) {
      const float4 w0 = *(const float4*)&gw_s[hh][j0];
      const float4 w1 = *(const float4*)&gw_s[hh][j1];
      f32x2 g0, g1, g2, g3;
      split4(w0, g0, g1); split4(w1, g2, g3);
      f32x2 d = q[0] * g0 + q[1] * g1 + q[2] * g2 + q[3] * g3;
      v8[hh] = d[0] + d[1];
    }
    s = wsum(s); ss = wsum(ss);
    const float mean = s * (1.f / 512.f);
    const float rstd = rsqrtf(ss * (1.f / 512.f) - mean * mean + 1e-5f);
    const float z = fold8(v8, lane);
    const float zf = rstd * 0.125f * (z - mean * sg_r) + bw8_r;
    if (lane < 8) sc_s[lane][k] = zf;
  }

  // ---- stage B: 72 cls rows, 9 pairs/wave, prefetch depth 2, f32x2 math
  f32x2 A2[8][4];
#pragma unroll
  for (int hh = 0; hh < 8; ++hh)
#pragma unroll
    for (int i = 0; i < 4; ++i) A2[hh][i] = f32x2{0.f, 0.f};
  float B8[8] = {}, L8[8] = {};

  const float* base = cls + (size_t)n * 72 * 512;
  float4 xa0, xa1, xb0, xb1, ya0, ya1, yb0, yb1;
  {
    const float* sA = base + (size_t)w * 512;
    const float* sB = base + (size_t)(w + 4) * 512;
    xa0 = *(const float4*)(sA + j0); xa1 = *(const float4*)(sA + j1);
    xb0 = *(const float4*)(sB + j0); xb1 = *(const float4*)(sB + j1);
    const float* sA1 = base + (size_t)(w + 8) * 512;
    const float* sB1 = base + (size_t)(w + 12) * 512;
    ya0 = *(const float4*)(sA1 + j0); ya1 = *(const float4*)(sA1 + j1);
    yb0 = *(const float4*)(sB1 + j0); yb1 = *(const float4*)(sB1 + j1);
  }
  for (int p = 0; p < 9; ++p) {
    float4 za0, za1, zb0, zb1;
    const bool more2 = (p + 2 < 9);
    if (more2) {
      const float* sA = base + (size_t)(w + 8 * (p + 2)) * 512;
      const float* sB = base + (size_t)(w + 4 + 8 * (p + 2)) * 512;
      za0 = *(const float4*)(sA + j0); za1 = *(const float4*)(sA + j1);
      zb0 = *(const float4*)(sB + j0); zb1 = *(const float4*)(sB + j1);
    }
    f32x2 qa[4], qb[4];
    split4(xa0, qa[0], qa[1]); split4(xa1, qa[2], qa[3]);
    split4(xb0, qb[0], qb[1]); split4(xb1, qb[2], qb[3]);
    f32x2 sa2 = qa[0] + qa[1] + qa[2] + qa[3];
    f32x2 ssa2 = qa[0] * qa[0] + qa[1] * qa[1] + qa[2] * qa[2] + qa[3] * qa[3];
    f32x2 sb2 = qb[0] + qb[1] + qb[2] + qb[3];
    f32x2 ssb2 = qb[0] * qb[0] + qb[1] * qb[1] + qb[2] * qb[2] + qb[3] * qb[3];
    float sa = sa2[0] + sa2[1], ssa = ssa2[0] + ssa2[1];
    float sb = sb2[0] + sb2[1], ssb = ssb2[0] + ssb2[1];
    float v8a[8], v8b[8];
#pragma unroll
    for (int hh = 0; hh < 8; ++hh) {
      const float4 w0 = *(const float4*)&gw_s[hh][j0];
      const float4 w1 = *(const float4*)&gw_s[hh][j1];
      f32x2 g0, g1, g2, g3;
      split4(w0, g0, g1); split4(w1, g2, g3);
      f32x2 da = qa[0] * g0 + qa[1] * g1 + qa[2] * g2 + qa[3] * g3;
      f32x2 db = qb[0] * g0 + qb[1] * g1 + qb[2] * g2 + qb[3] * g3;
      v8a[hh] = da[0] + da[1];
      v8b[hh] = db[0] + db[1];
    }
    sa = wsum(sa); ssa = wsum(ssa); sb = wsum(sb); ssb = wsum(ssb);
    const float meanA = sa * (1.f / 512.f);
    const float rstdA = rsqrtf(ssa * (1.f / 512.f) - meanA * meanA + 1e-5f);
    const float meanB = sb * (1.f / 512.f);
    const float rstdB = rsqrtf(ssb * (1.f / 512.f) - meanB * meanB + 1e-5f);
    const float za = fold8(v8a, lane);
    const float zb = fold8(v8b, lane);
    const float zfa = rstdA * 0.125f * (za - meanA * sg_r) + bw8_r;
    const float zfb = rstdB * 0.125f * (zb - meanB * sg_r) + bw8_r;
    const int kA = 5 + w + 8 * p;
    if (lane < 8) {
      sc_s[lane][kA] = zfa; sc_s[lane][kA + 4] = zfb;
      es_s[w][0][lane] = __expf(zfa);
      es_s[w][1][lane] = __expf(zfb);
    }
    __builtin_amdgcn_wave_barrier();
    const float4 ea0 = *(const float4*)&es_s[w][0][0];
    const float4 ea1 = *(const float4*)&es_s[w][0][4];
    const float4 eb0 = *(const float4*)&es_s[w][1][0];
    const float4 eb1 = *(const float4*)&es_s[w][1][4];
    const float esa[8] = {ea0.x, ea0.y, ea0.z, ea0.w, ea1.x, ea1.y, ea1.z, ea1.w};
    const float esb[8] = {eb0.x, eb0.y, eb0.z, eb0.w, eb1.x, eb1.y, eb1.z, eb1.w};
#pragma unroll
    for (int hh = 0; hh < 8; ++hh) {
      const float erA = esa[hh] * rstdA;
      const float erB = esb[hh] * rstdB;
      const f32x2 eA = f32x2{erA, erA};
      const f32x2 eB = f32x2{erB, erB};
      A2[hh][0] += eA * qa[0]; A2[hh][1] += eA * qa[1];
      A2[hh][2] += eA * qa[2]; A2[hh][3] += eA * qa[3];
      A2[hh][0] += eB * qb[0]; A2[hh][1] += eB * qb[1];
      A2[hh][2] += eB * qb[2]; A2[hh][3] += eB * qb[3];
      B8[hh] += erA * meanA + erB * meanB;
      L8[hh] += esa[hh] + esb[hh];
    }
    xa0 = ya0; xa1 = ya1; xb0 = yb0; xb1 = yb1;
    if (more2) { ya0 = za0; ya1 = za1; yb0 = zb0; yb1 = zb1; }
  }
  if (lane == 0)
#pragma unroll
    for (int hh = 0; hh < 8; ++hh) {
      wstatB[w][hh] = B8[hh]; wstatL[w][hh] = L8[hh];
    }
  __syncthreads();

  // ---- pass-1 softmax over 77 -> head-mean of first 5 -> attr
  for (int hh = w; hh < 8; hh += 4) {
    const float v0 = sc_s[hh][lane];
    const float v1 = (lane + 64 < 77) ? sc_s[hh][lane + 64] : -1e30f;
    const float mx = wmaxr(fmaxf(v0, v1));
    const float e0 = __expf(v0 - mx);
    const float e1 = (lane + 64 < 77) ? __expf(v1 - mx) : 0.f;
    const float S = wsum(e0 + e1);
    if (lane < 5) ah_s[hh][lane] = e0 / S;
  }
  __syncthreads();
  if (tid == 0) {
    float m[5], mx = -1e30f;
#pragma unroll
    for (int p = 0; p < 5; ++p) {
      float acc = 0.f;
      for (int hh = 0; hh < 8; ++hh) acc += ah_s[hh][p];
      m[p] = acc * 0.125f;
      mx = fmaxf(mx, m[p]);
    }
    float e[5], S = 0.f;
#pragma unroll
    for (int p = 0; p < 5; ++p) { e[p] = __expf(m[p] - mx); S += e[p]; }
#pragma unroll
    for (int p = 0; p < 5; ++p) attr_s[p] = e[p] / S;
  }
  __syncthreads();

  // ---- stage C: scaled ctx rows (global reads) -> h2 (bf16 LDS) + sc2
  for (int k = w; k < 5; k += 4) {
    const float c = attr_s[k];
    const float* src = ctx + ((size_t)n * 5 + k) * 512;
    float4 x0 = *(const float4*)(src + j0);
    float4 x1 = *(const float4*)(src + j1);
    x0.x *= c; x0.y *= c; x0.z *= c; x0.w *= c;
    x1.x *= c; x1.y *= c; x1.z *= c; x1.w *= c;
    f32x2 q[4];
    split4(x0, q[0], q[1]); split4(x1, q[2], q[3]);
    f32x2 s2v = q[0] + q[1] + q[2] + q[3];
    f32x2 ss2 = q[0] * q[0] + q[1] * q[1] + q[2] * q[2] + q[3] * q[3];
    float s  = s2v[0] + s2v[1];
    float ss = ss2[0] + ss2[1];
    float v8[8];
#pragma unroll
    for (int hh = 0; hh < 8; ++hh) {
      const float4 w0 = *(const float4*)&gw_s[hh][j0];
      const float4 w1 = *(const float4*)&gw_s[hh][j1];
      f32x2 g0, g1, g2, g3;
      split4(w0, g0, g1); split4(w1, g2, g3);
      f32x2 d = q[0] * g0 + q[1] * g1 + q[2] * g2 + q[3] * g3;
      v8[hh] = d[0] + d[1];
    }
    s = wsum(s); ss = wsum(ss);
    const float mean = s * (1.f / 512.f);
    const float rstd = rsqrtf(ss * (1.f / 512.f) - mean * mean + 1e-5f);
    {
      const float4 gg0 = *(const float4*)&g_s[j0];
      const float4 bb0 = *(const float4*)&b_s[j0];
      const float4 gg1 = *(const float4*)&g_s[j1];
      const float4 bb1 = *(const float4*)&b_s[j1];
      s16x4 o0, o1;
      o0[0] = f2bf((x0.x - mean) * rstd * gg0.x + bb0.x);
      o0[1] = f2bf((x0.y - mean) * rstd * gg0.y + bb0.y);
      o0[2] = f2bf((x0.z - mean) * rstd * gg0.z + bb0.z);
      o0[3] = f2bf((x0.w - mean) * rstd * gg0.w + bb0.w);
      o1[0] = f2bf((x1.x - mean) * rstd * gg1.x + bb1.x);
      o1[1] = f2bf((x1.y - mean) * rstd * gg1.y + bb1.y);
      o1[2] = f2bf((x1.z - mean) * rstd * gg1.z + bb1.z);
      o1[3] = f2bf((x1.w - mean) * rstd * gg1.w + bb1.w);
      *(s16x4*)&h2_s[k][j0] = o0;
      *(s16x4*)&h2_s[k][j1] = o1;
    }
    const float z = fold8(v8, lane);
    const float zf = rstd * 0.125f * (z - mean * sg_r) + bw8_r;
    if (lane < 8) sc2_s[lane][k] = zf;
  }
  __syncthreads();

  // ---- cross-wave A combine into gw_s region (float4)
  for (int wv = 0; wv < 4; ++wv) {
    if (w == wv) {
#pragma unroll
      for (int hh = 0; hh < 8; ++hh) {
        float4* p0 = (float4*)&gw_s[hh][j0];
        float4* p1 = (float4*)&gw_s[hh][j1];
        const float4 a0 = make_float4(A2[hh][0][0], A2[hh][0][1],
                                      A2[hh][1][0], A2[hh][1][1]);
        const float4 a1 = make_float4(A2[hh][2][0], A2[hh][2][1],
                                      A2[hh][3][0], A2[hh][3][1]);
        if (wv == 0) { *p0 = a0; *p1 = a1; }
        else {
          float4 v0 = *p0, v1 = *p1;
          v0.x += a0.x; v0.y += a0.y; v0.z += a0.z; v0.w += a0.w;
          v1.x += a1.x; v1.y += a1.y; v1.z += a1.z; v1.w += a1.w;
          *p0 = v0; *p1 = v1;
        }
      }
    }
    __syncthreads();
  }

  if (tid < 8) {
    float Bt = 0.f, Lt = 0.f;
    for (int wv = 0; wv < 4; ++wv) { Bt += wstatB[wv][tid]; Lt += wstatL[wv][tid]; }
    float den = Lt;
#pragma unroll
    for (int k = 0; k < 5; ++k) {
      const float e = __expf(sc2_s[tid][k]);
      e2_s[tid][k] = e; den += e;
    }
    Bt_s[tid] = Bt; Lt_s[tid] = Lt; inv_s[tid] = 1.f / den;
  }
  __syncthreads();

  // ---- u[hh][j] (bf16) = ((g*(A-B) + b*L + sum_k e2*h2) / den)
  __hip_bfloat16* dst = u_out + (size_t)n * 4096;
  for (int bidx = tid * 4; bidx < 4096; bidx += 1024) {
    const int hh = bidx >> 9, j = bidx & 511;
    const float4 a4 = *(const float4*)&gw_s[hh][j];
    const float4 g4 = *(const float4*)&g_s[j];
    const float4 b4 = *(const float4*)&b_s[j];
    const float Bt = Bt_s[hh], Lt = Lt_s[hh];
    float v0 = (a4.x - Bt) * g4.x + Lt * b4.x;
    float v1 = (a4.y - Bt) * g4.y + Lt * b4.y;
    float v2 = (a4.z - Bt) * g4.z + Lt * b4.z;
    float v3 = (a4.w - Bt) * g4.w + Lt * b4.w;
#pragma unroll
    for (int k = 0; k < 5; ++k) {
      const s16x4 hq = *(const s16x4*)&h2_s[k][j];
      const float e = e2_s[hh][k];
      v0 += e * bfs2f(hq[0]); v1 += e * bfs2f(hq[1]);
      v2 += e * bfs2f(hq[2]); v3 += e * bfs2f(hq[3]);
    }
    const float iv = inv_s[hh];
    s16x4 o;
    o[0] = f2bf(v0 * iv); o[1] = f2bf(v1 * iv);
    o[2] = f2bf(v2 * iv); o[3] = f2bf(v3 * iv);
    *(s16x4*)&dst[bidx] = o;
  }
}

// ---------------------------------------------------------------------------
extern "C" void kernel_launch(void* const* d_in, const int* in_sizes, int n_in,
                              void* d_out, int out_size, void* d_ws, size_t ws_size,
                              hipStream_t stream)
{
  const float* images = (const float*)d_in[0];
  const float* W_img  = (const float*)d_in[1];
  const float* ctx    = (const float*)d_in[2];
  const float* cls    = (const float*)d_in[3];
  const float* ln_g   = (const float*)d_in[4];
  const float* ln_b   = (const float*)d_in[5];
  const float* Wq     = (const float*)d_in[6];
  const float* Wk     = (const float*)d_in[7];
  const float* Wv     = (const float*)d_in[8];
  const float* Wo     = (const float*)d_in[9];
  const float* tproj  = (const float*)d_in[10];
  const float* lscale = (const float*)d_in[11];

  __hip_bfloat16* wtu = (__hip_bfloat16*)d_ws;  // wt -> u (bf16, in place)
  float* fws  = (float*)d_ws;
  float* img  = fws + 2048000;
  float* hlO  = img + 131072;       // O
  float* qo2  = hlO + 512000;       // q -> out2
  float* txt  = fws;                // alias over dead u region
  (void)in_sizes; (void)n_in; (void)out_size; (void)ws_size;

  // 1) image embedding (32-tile MFMA, grid 64), unnormalized
  gemm32_mfma_k<0,0><<<dim3(8,8,1),256,0,stream>>>(images,768,0, W_img,512,0,
      img,512,0, nullptr,0, 256,512,768);

  // 2) q = LN(cls_last) @ Wq  (LN fused into staging)
  gemm_mfma_lnA_k<<<dim3(8,16),256,0,stream>>>(cls + 71*512, 72*512,
      ln_g, ln_b, Wq,512, qo2,512, 1000,512,512);

  // 3) wt = per-head q @ Wk^T  -> bf16 (grid 1024, 64-tile)
  gemm_mfma_k<1,0,0,1><<<dim3(8,16,8),256,0,stream>>>(qo2,512,64, Wk,512,64,
      wtu,4096,512, nullptr,0, 1000,512,64);

  // 4+5) fused pass1+pass2 sweep -> u bf16 (in place over wt)
  fused_sweep_kernel<<<1000,256,0,stream>>>(ctx, cls, ln_g, ln_b, wtu, wtu);

  // 6) O = per-head u @ Wv  (32-tile MFMA, 256 blocks, A read as bf16)
  gemm32_mfma_k<0,1><<<dim3(1,32,8),256,0,stream>>>(wtu,4096,512, Wv,512,64,
      hlO,512,64, nullptr,0, 1000,64,512);

  // 7) out2 = cls_last + O @ Wo ; txt = out2 @ text_proj  (32-tile MFMA)
  gemm32_mfma_k<1,0><<<dim3(8,32,1),256,0,stream>>>(hlO,512,0, Wo,512,0,
      qo2,512,0, cls + 71*512, 72*512, 1000,512,512);
  gemm32_mfma_k<0,0><<<dim3(8,32,1),256,0,stream>>>(qo2,512,0, tproj,512,0,
      txt,512,0, nullptr,0, 1000,512,512);

  // 8) logits = exp(ls) * (img/|img|) @ (txt/|txt|)^T  (MFMA, norms fused
  //    from f32 at load; only the dot is bf16)
  logits_mfma_k<<<dim3(16,8),256,0,stream>>>(img,512, txt,512,
      (float*)d_out,1000, lscale, 256,1000,512);
}